// Round 1
// baseline (301.285 us; speedup 1.0000x reference)
//
#include <hip/hip_runtime.h>
#include <hip/hip_bf16.h>

constexpr int B = 2, S = 2048, D = 1024, H = 16, DK = 64;
constexpr int M = B * S;
constexpr float LOG2E = 1.44269504088896f;
constexpr float NEGBIG = -3.0e38f;

using short8 = __attribute__((ext_vector_type(8))) short;
using short4v = __attribute__((ext_vector_type(4))) short;
using f32x4 = __attribute__((ext_vector_type(4))) float;

__device__ __forceinline__ short f2bf(float f) {
  union { float f; unsigned u; } c; c.f = f;
  unsigned u = c.u;
  u += 0x7fffu + ((u >> 16) & 1u);
  return (short)(u >> 16);
}
__device__ __forceinline__ float bf2f(short s) {
  union { unsigned u; float f; } c;
  c.u = ((unsigned)(unsigned short)s) << 16;
  return c.f;
}

// ---- fp32 -> bf16 convert (vectorized) ----
__global__ __launch_bounds__(256) void cvt_bf16_kernel(const float* __restrict__ in,
                                                       short* __restrict__ out, int n4) {
  int i = blockIdx.x * 256 + threadIdx.x;
  if (i >= n4) return;
  float4 v = ((const float4*)in)[i];
  short4v o;
  o[0] = f2bf(v.x); o[1] = f2bf(v.y); o[2] = f2bf(v.z); o[3] = f2bf(v.w);
  ((short4v*)out)[i] = o;
}

// ---- weight transpose + convert: Wt[n][k] = bf16(W[k][n]) ----
__global__ __launch_bounds__(256) void transw_kernel(const float* __restrict__ W,
                                                     short* __restrict__ Wt) {
  __shared__ float t[64][65];
  const int k0 = blockIdx.y * 64, n0 = blockIdx.x * 64;
  const int lx = threadIdx.x & 63, ly = threadIdx.x >> 6;
  #pragma unroll
  for (int r = 0; r < 64; r += 4)
    t[r + ly][lx] = W[(size_t)(k0 + r + ly) * D + n0 + lx];
  __syncthreads();
  #pragma unroll
  for (int r = 0; r < 64; r += 4)
    Wt[(size_t)(n0 + r + ly) * D + k0 + lx] = f2bf(t[lx][r + ly]);
}

// ---- bf16 GEMM: C[M][N] = A[M][K] * Bt[N][K]^T, 128x128 tile, BK=32, 4 waves ----
template <int OUT_BF16>
__global__ __launch_bounds__(256) void gemm_bt_kernel(const short* __restrict__ A,
                                                      const short* __restrict__ Bt,
                                                      void* __restrict__ Cv,
                                                      int N, int K) {
  __shared__ short As[4][128][8];  // [k-chunk of 8][row][8]
  __shared__ short Bs[4][128][8];
  const int tid = threadIdx.x;
  const int lane = tid & 63, wid = tid >> 6;
  const int l15 = lane & 15, lg = lane >> 4;
  const int row0 = blockIdx.y * 128, col0 = blockIdx.x * 128;
  const int wm = wid >> 1, wn = wid & 1;
  f32x4 acc[4][4] = {};
  const int sr = tid >> 2;        // 0..63
  const int co = (tid & 3) * 8;   // 0,8,16,24

  for (int k0 = 0; k0 < K; k0 += 32) {
    __syncthreads();
    #pragma unroll
    for (int it = 0; it < 2; ++it) {
      const int rr = sr + it * 64;
      *(short8*)&As[co >> 3][rr][0] = *(const short8*)&A[(size_t)(row0 + rr) * K + k0 + co];
      *(short8*)&Bs[co >> 3][rr][0] = *(const short8*)&Bt[(size_t)(col0 + rr) * K + k0 + co];
    }
    __syncthreads();
    short8 af[4], bfr[4];
    #pragma unroll
    for (int m = 0; m < 4; ++m) af[m] = *(const short8*)&As[lg][wm * 64 + m * 16 + l15][0];
    #pragma unroll
    for (int n = 0; n < 4; ++n) bfr[n] = *(const short8*)&Bs[lg][wn * 64 + n * 16 + l15][0];
    #pragma unroll
    for (int m = 0; m < 4; ++m)
      #pragma unroll
      for (int n = 0; n < 4; ++n)
        acc[m][n] = __builtin_amdgcn_mfma_f32_16x16x32_bf16(af[m], bfr[n], acc[m][n], 0, 0, 0);
  }
  #pragma unroll
  for (int m = 0; m < 4; ++m) {
    #pragma unroll
    for (int r = 0; r < 4; ++r) {
      const int row = row0 + wm * 64 + m * 16 + 4 * lg + r;
      #pragma unroll
      for (int n = 0; n < 4; ++n) {
        const int col = col0 + wn * 64 + n * 16 + l15;
        if (OUT_BF16)
          ((short*)Cv)[(size_t)row * N + col] = f2bf(acc[m][n][r]);
        else
          ((float*)Cv)[(size_t)row * N + col] = acc[m][n][r];
      }
    }
  }
}

// ---- V column means (for padding-masked query rows) ----
__global__ __launch_bounds__(256) void vmean_part_kernel(const short* __restrict__ Vb,
                                                         float* __restrict__ part) {
  const int d = blockIdx.x * 256 + threadIdx.x;  // 0..1023
  const int c = blockIdx.y;                      // 0..15
  const int b = blockIdx.z;
  float s = 0.f;
  for (int i = 0; i < S / 16; ++i)
    s += bf2f(Vb[(size_t)(b * S + c * (S / 16) + i) * D + d]);
  part[((size_t)b * 16 + c) * D + d] = s;
}
__global__ __launch_bounds__(256) void vmean_final_kernel(const float* __restrict__ part,
                                                          float* __restrict__ vmean) {
  const int d = blockIdx.x * 256 + threadIdx.x;
  const int b = blockIdx.y;
  float s = 0.f;
  #pragma unroll
  for (int c = 0; c < 16; ++c) s += part[((size_t)b * 16 + c) * D + d];
  vmean[(size_t)b * D + d] = s * (1.0f / S);
}

// ---- causal flash attention, 64 q-rows per block, 4 waves x 16 rows ----
__global__ __launch_bounds__(256) void attn_kernel(const short* __restrict__ Qb,
                                                   const short* __restrict__ Kb,
                                                   const short* __restrict__ Vb,
                                                   const int* __restrict__ maskp,
                                                   const float* __restrict__ vmean,
                                                   short* __restrict__ ctxb) {
  __shared__ short Ks[8][64][8];     // [d-chunk][key][8]
  __shared__ short Vt[8][64][8];     // [k-chunk][d][8]  (transposed V)
  __shared__ short Ps[4][8][16][8];  // per-wave P restage [k-chunk][q][8]
  const int qb = blockIdx.x, h = blockIdx.y, b = blockIdx.z;
  const int q0 = qb * 64;
  const int tid = threadIdx.x;
  const int lane = tid & 63, wid = tid >> 6;
  const int l15 = lane & 15, lg = lane >> 4;

  short8 qf[2];
  {
    const size_t qoff = (size_t)(b * S + q0 + wid * 16 + l15) * D + h * DK;
    qf[0] = *(const short8*)&Qb[qoff + lg * 8];
    qf[1] = *(const short8*)&Qb[qoff + 32 + lg * 8];
  }
  float m_r[4], l_r[4];
  f32x4 ctx[4];
  #pragma unroll
  for (int r = 0; r < 4; ++r) { m_r[r] = NEGBIG; l_r[r] = 0.f; }
  #pragma unroll
  for (int dt = 0; dt < 4; ++dt) ctx[dt] = f32x4{0.f, 0.f, 0.f, 0.f};

  const int sr = tid >> 2;         // key row 0..63
  const int d0 = (tid & 3) * 16;   // d offset

  for (int j = 0; j <= qb; ++j) {
    __syncthreads();
    {
      const size_t base = (size_t)(b * S + j * 64 + sr) * D + h * DK + d0;
      const short8 kv0 = *(const short8*)&Kb[base];
      const short8 kv1 = *(const short8*)&Kb[base + 8];
      const short8 vv0 = *(const short8*)&Vb[base];
      const short8 vv1 = *(const short8*)&Vb[base + 8];
      *(short8*)&Ks[d0 >> 3][sr][0] = kv0;
      *(short8*)&Ks[(d0 >> 3) + 1][sr][0] = kv1;
      const int kc = sr >> 3, ksb = sr & 7;
      #pragma unroll
      for (int i = 0; i < 8; ++i) Vt[kc][d0 + i][ksb] = kv0[i], Vt[kc][d0 + i][ksb] = vv0[i];
      #pragma unroll
      for (int i = 0; i < 8; ++i) Vt[kc][d0 + 8 + i][ksb] = vv1[i];
    }
    __syncthreads();

    f32x4 sa[4];
    #pragma unroll
    for (int c = 0; c < 4; ++c) {
      const short8 kf0 = *(const short8*)&Ks[lg][c * 16 + l15][0];
      const short8 kf1 = *(const short8*)&Ks[4 + lg][c * 16 + l15][0];
      f32x4 z = {0.f, 0.f, 0.f, 0.f};
      z = __builtin_amdgcn_mfma_f32_16x16x32_bf16(qf[0], kf0, z, 0, 0, 0);
      z = __builtin_amdgcn_mfma_f32_16x16x32_bf16(qf[1], kf1, z, 0, 0, 0);
      sa[c] = z * 0.125f;  // 1/sqrt(64)
    }
    if (j == qb) {  // diagonal tile: strict causal mask
      #pragma unroll
      for (int c = 0; c < 4; ++c) {
        const int key = c * 16 + l15;
        #pragma unroll
        for (int r = 0; r < 4; ++r) {
          const int qrow = wid * 16 + 4 * lg + r;
          if (key > qrow) sa[c][r] = NEGBIG;
        }
      }
    }
    #pragma unroll
    for (int r = 0; r < 4; ++r) {
      float v = fmaxf(fmaxf(sa[0][r], sa[1][r]), fmaxf(sa[2][r], sa[3][r]));
      v = fmaxf(v, __shfl_xor(v, 1));
      v = fmaxf(v, __shfl_xor(v, 2));
      v = fmaxf(v, __shfl_xor(v, 4));
      v = fmaxf(v, __shfl_xor(v, 8));
      const float mn = fmaxf(m_r[r], v);
      const float sc = exp2f((m_r[r] - mn) * LOG2E);
      m_r[r] = mn;
      float rsum = 0.f;
      #pragma unroll
      for (int c = 0; c < 4; ++c) {
        const float p = exp2f((sa[c][r] - mn) * LOG2E);
        sa[c][r] = p;
        rsum += p;
      }
      rsum += __shfl_xor(rsum, 1);
      rsum += __shfl_xor(rsum, 2);
      rsum += __shfl_xor(rsum, 4);
      rsum += __shfl_xor(rsum, 8);
      l_r[r] = l_r[r] * sc + rsum;
      #pragma unroll
      for (int dt = 0; dt < 4; ++dt) ctx[dt][r] *= sc;
    }
    // restage P (16 x 64 per wave) into A-fragment layout
    #pragma unroll
    for (int c = 0; c < 4; ++c) {
      const int kc = c * 2 + (l15 >> 3);
      const int sub = l15 & 7;
      #pragma unroll
      for (int r = 0; r < 4; ++r)
        Ps[wid][kc][4 * lg + r][sub] = f2bf(sa[c][r]);
    }
    __syncthreads();
    #pragma unroll
    for (int kk = 0; kk < 2; ++kk) {
      const short8 pf = *(const short8*)&Ps[wid][kk * 4 + lg][l15][0];
      #pragma unroll
      for (int dt = 0; dt < 4; ++dt) {
        const short8 vf = *(const short8*)&Vt[kk * 4 + lg][dt * 16 + l15][0];
        ctx[dt] = __builtin_amdgcn_mfma_f32_16x16x32_bf16(pf, vf, ctx[dt], 0, 0, 0);
      }
    }
  }
  // epilogue: normalize; masked query rows -> mean(V)
  #pragma unroll
  for (int r = 0; r < 4; ++r) {
    const int q = q0 + wid * 16 + 4 * lg + r;
    const int mq = maskp[b * S + q];
    const float inv = 1.0f / l_r[r];
    #pragma unroll
    for (int dt = 0; dt < 4; ++dt) {
      const int d = dt * 16 + l15;
      const float val = (mq != 0) ? vmean[(size_t)b * D + h * DK + d] : ctx[dt][r] * inv;
      ctxb[(size_t)(b * S + q) * D + h * DK + d] = f2bf(val);
    }
  }
}

extern "C" void kernel_launch(void* const* d_in, const int* in_sizes, int n_in,
                              void* d_out, int out_size, void* d_ws, size_t ws_size,
                              hipStream_t stream) {
  (void)in_sizes; (void)n_in; (void)out_size; (void)ws_size;
  const float* x   = (const float*)d_in[0];
  const float* enc = (const float*)d_in[1];
  const int*   msk = (const int*)d_in[2];
  const float* WQ  = (const float*)d_in[3];
  const float* WK  = (const float*)d_in[4];
  const float* WV  = (const float*)d_in[5];
  const float* WO  = (const float*)d_in[6];
  float* out = (float*)d_out;

  char* ws = (char*)d_ws;
  const size_t MB = 1u << 20;
  short* xb    = (short*)(ws + 0);          // 8 MB  (reused as ctxb)
  short* encb  = (short*)(ws + 8 * MB);     // 8 MB
  short* Qb    = (short*)(ws + 16 * MB);    // 8 MB
  short* Kb    = (short*)(ws + 24 * MB);    // 8 MB
  short* Vb    = (short*)(ws + 32 * MB);    // 8 MB
  short* WQt   = (short*)(ws + 40 * MB);    // 2 MB each
  short* WKt   = (short*)(ws + 42 * MB);
  short* WVt   = (short*)(ws + 44 * MB);
  short* WOt   = (short*)(ws + 46 * MB);
  float* vpart = (float*)(ws + 48 * MB);            // 128 KB
  float* vmean = (float*)(ws + 48 * MB + 131072);   // 8 KB
  short* ctxb  = xb;

  const int n4 = M * D / 4;
  cvt_bf16_kernel<<<n4 / 256, 256, 0, stream>>>(x, xb, n4);
  cvt_bf16_kernel<<<n4 / 256, 256, 0, stream>>>(enc, encb, n4);
  dim3 tg(16, 16);
  transw_kernel<<<tg, 256, 0, stream>>>(WQ, WQt);
  transw_kernel<<<tg, 256, 0, stream>>>(WK, WKt);
  transw_kernel<<<tg, 256, 0, stream>>>(WV, WVt);
  transw_kernel<<<tg, 256, 0, stream>>>(WO, WOt);

  dim3 gg(D / 128, M / 128);  // (8, 32)
  gemm_bt_kernel<1><<<gg, 256, 0, stream>>>(xb,   WQt, Qb, D, D);
  gemm_bt_kernel<1><<<gg, 256, 0, stream>>>(encb, WKt, Kb, D, D);
  gemm_bt_kernel<1><<<gg, 256, 0, stream>>>(encb, WVt, Vb, D, D);

  vmean_part_kernel<<<dim3(D / 256, 16, B), 256, 0, stream>>>(Vb, vpart);
  vmean_final_kernel<<<dim3(D / 256, B), 256, 0, stream>>>(vpart, vmean);

  attn_kernel<<<dim3(S / 64, H, B), 256, 0, stream>>>(Qb, Kb, Vb, msk, vmean, ctxb);

  gemm_bt_kernel<0><<<gg, 256, 0, stream>>>(ctxb, WOt, out, D, D);
}

// Round 2
// 248.809 us; speedup vs baseline: 1.2109x; 1.2109x over previous
//
#include <hip/hip_runtime.h>
#include <hip/hip_bf16.h>

constexpr int B = 2, S = 2048, D = 1024, H = 16, DK = 64;
constexpr int M = B * S;
constexpr float LOG2E = 1.44269504088896f;
constexpr float NEGBIG = -3.0e38f;

using short8 = __attribute__((ext_vector_type(8))) short;
using short4v = __attribute__((ext_vector_type(4))) short;
using f32x4 = __attribute__((ext_vector_type(4))) float;

#define GLOBAL_AS __attribute__((address_space(1)))
#define LDS_AS __attribute__((address_space(3)))

__device__ __forceinline__ void gll16(const void* g, void* l) {
  __builtin_amdgcn_global_load_lds((const GLOBAL_AS void*)g, (LDS_AS void*)l, 16, 0, 0);
}

__device__ __forceinline__ short f2bf(float f) {
  union { float f; unsigned u; } c; c.f = f;
  unsigned u = c.u;
  u += 0x7fffu + ((u >> 16) & 1u);
  return (short)(u >> 16);
}
__device__ __forceinline__ float bf2f(short s) {
  union { unsigned u; float f; } c;
  c.u = ((unsigned)(unsigned short)s) << 16;
  return c.f;
}
__device__ __forceinline__ unsigned pack2bf(float a, float b) {
  return (unsigned)(unsigned short)f2bf(a) | ((unsigned)(unsigned short)f2bf(b) << 16);
}

// ---- fp32 -> bf16 convert (vectorized) ----
__global__ __launch_bounds__(256) void cvt_bf16_kernel(const float* __restrict__ in,
                                                       short* __restrict__ out, int n4) {
  int i = blockIdx.x * 256 + threadIdx.x;
  if (i >= n4) return;
  float4 v = ((const float4*)in)[i];
  short4v o;
  o[0] = f2bf(v.x); o[1] = f2bf(v.y); o[2] = f2bf(v.z); o[3] = f2bf(v.w);
  ((short4v*)out)[i] = o;
}

// ---- weight transpose + convert: Wt[n][k] = bf16(W[k][n]) ----
__global__ __launch_bounds__(256) void transw_kernel(const float* __restrict__ W,
                                                     short* __restrict__ Wt) {
  __shared__ float t[64][65];
  const int k0 = blockIdx.y * 64, n0 = blockIdx.x * 64;
  const int lx = threadIdx.x & 63, ly = threadIdx.x >> 6;
  #pragma unroll
  for (int r = 0; r < 64; r += 4)
    t[r + ly][lx] = W[(size_t)(k0 + r + ly) * D + n0 + lx];
  __syncthreads();
  #pragma unroll
  for (int r = 0; r < 64; r += 4)
    Wt[(size_t)(n0 + r + ly) * D + k0 + lx] = f2bf(t[lx][r + ly]);
}

// ---- bf16 GEMM (m97 structure): C = A[M][K] * Bt[N][K]^T, 128x128 tile, BK=32 ----
template <int OUT_BF16>
__global__ __launch_bounds__(256) void gemm_bt_kernel(const short* __restrict__ A,
                                                      const short* __restrict__ Bt,
                                                      void* __restrict__ Cv,
                                                      int N, int K, float oscale) {
  __shared__ short As[4][128][8];  // [k-chunk of 8][row][8]
  __shared__ short Bs[4][128][8];
  const int tid = threadIdx.x;
  const int lane = tid & 63, wid = tid >> 6;
  const int l15 = lane & 15, lg = lane >> 4;
  const int row0 = blockIdx.y * 128, col0 = blockIdx.x * 128;
  const int wm = wid >> 1, wn = wid & 1;
  f32x4 acc[4][4] = {};

  for (int k0 = 0; k0 < K; k0 += 32) {
    __syncthreads();
    #pragma unroll
    for (int it = 0; it < 2; ++it) {
      const int t = tid + it * 256;           // 0..511
      const int row = t & 127, kc2 = t >> 7;  // wave-uniform kc2
      gll16(&A[(size_t)(row0 + row) * K + k0 + kc2 * 8],
            (char*)As + (size_t)(wid * 64 + it * 256) * 16);
      gll16(&Bt[(size_t)(col0 + row) * K + k0 + kc2 * 8],
            (char*)Bs + (size_t)(wid * 64 + it * 256) * 16);
    }
    __syncthreads();
    short8 af[4], bfr[4];
    #pragma unroll
    for (int m = 0; m < 4; ++m) af[m] = *(const short8*)&As[lg][wm * 64 + m * 16 + l15][0];
    #pragma unroll
    for (int n = 0; n < 4; ++n) bfr[n] = *(const short8*)&Bs[lg][wn * 64 + n * 16 + l15][0];
    #pragma unroll
    for (int m = 0; m < 4; ++m)
      #pragma unroll
      for (int n = 0; n < 4; ++n)
        acc[m][n] = __builtin_amdgcn_mfma_f32_16x16x32_bf16(af[m], bfr[n], acc[m][n], 0, 0, 0);
  }
  #pragma unroll
  for (int m = 0; m < 4; ++m) {
    #pragma unroll
    for (int r = 0; r < 4; ++r) {
      const int row = row0 + wm * 64 + m * 16 + 4 * lg + r;
      #pragma unroll
      for (int n = 0; n < 4; ++n) {
        const int col = col0 + wn * 64 + n * 16 + l15;
        if (OUT_BF16)
          ((short*)Cv)[(size_t)row * N + col] = f2bf(acc[m][n][r] * oscale);
        else
          ((float*)Cv)[(size_t)row * N + col] = acc[m][n][r] * oscale;
      }
    }
  }
}

// ---- V column means (for padding-masked query rows) ----
__global__ __launch_bounds__(256) void vmean_part_kernel(const short* __restrict__ Vb,
                                                         float* __restrict__ part) {
  const int d = blockIdx.x * 256 + threadIdx.x;
  const int c = blockIdx.y;
  const int b = blockIdx.z;
  float s = 0.f;
  for (int i = 0; i < S / 16; ++i)
    s += bf2f(Vb[(size_t)(b * S + c * (S / 16) + i) * D + d]);
  part[((size_t)b * 16 + c) * D + d] = s;
}
__global__ __launch_bounds__(256) void vmean_final_kernel(const float* __restrict__ part,
                                                          float* __restrict__ vmean) {
  const int d = blockIdx.x * 256 + threadIdx.x;
  const int b = blockIdx.y;
  float s = 0.f;
  #pragma unroll
  for (int c = 0; c < 16; ++c) s += part[((size_t)b * 16 + c) * D + d];
  vmean[(size_t)b * D + d] = s * (1.0f / S);
}

// key permutation: QK chunk c, MFMA row i -> key
__device__ __forceinline__ int keyof(int c, int i) {
  return ((c >> 1) << 5) + ((i >> 2) << 3) + ((c & 1) << 2) + (i & 3);
}
// swizzled Vt byte address: Vt[kc][d][ksb] = V[kc*8+ksb][d]
__device__ __forceinline__ int vt_byte(int kc, int d, int ksb) {
  return kc * 1024 + ((d ^ (kc & 7)) << 4) + ksb * 2;
}

// ---- causal flash attention: paired q-tiles (i, 31-i), swapped QK^T, P in regs ----
__global__ __launch_bounds__(256) void attn_kernel(const short* __restrict__ Qb,
                                                   const short* __restrict__ Kb,
                                                   const short* __restrict__ Vb,
                                                   const int* __restrict__ maskp,
                                                   const float* __restrict__ vmean,
                                                   short* __restrict__ ctxb) {
  __shared__ short Ks[8][4][16][8];  // [dc][c][i][8]: K[keyof(c,i)][dc*8+j]
  __shared__ short Vt[4096];         // swizzled, see vt_byte
  const int iblk = blockIdx.x, h = blockIdx.y, b = blockIdx.z;
  const int qtA = iblk, qtB = 31 - iblk;
  const int tid = threadIdx.x, lane = tid & 63, wid = tid >> 6;
  const int l15 = lane & 15, lg = lane >> 4;

  short8 qfA[2], qfB[2];
  {
    const size_t oA = (size_t)(b * S + qtA * 64 + wid * 16 + l15) * D + h * DK;
    const size_t oB = (size_t)(b * S + qtB * 64 + wid * 16 + l15) * D + h * DK;
    qfA[0] = *(const short8*)&Qb[oA + lg * 8];
    qfA[1] = *(const short8*)&Qb[oA + 32 + lg * 8];
    qfB[0] = *(const short8*)&Qb[oB + lg * 8];
    qfB[1] = *(const short8*)&Qb[oB + 32 + lg * 8];
  }
  float mA = NEGBIG, lA = 0.f, mB = NEGBIG, lB = 0.f;
  f32x4 cA[4] = {}, cB[4] = {};

  const int kkey = keyof(lane >> 4, lane & 15);  // K staging key for this lane
  const int vu = tid & 31, ve = tid >> 5;        // V staging map

  auto tile = [&](const short8* qf, float& m, float& l, f32x4* cx, bool diag) {
    f32x4 sa[4];
    #pragma unroll
    for (int c = 0; c < 4; ++c) {
      const short8 kf0 = *(const short8*)((char*)Ks + (0 * 4 + lg) * 1024 + c * 256 + l15 * 16);
      const short8 kf1 = *(const short8*)((char*)Ks + (1 * 4 + lg) * 1024 + c * 256 + l15 * 16);
      f32x4 z = {0.f, 0.f, 0.f, 0.f};
      z = __builtin_amdgcn_mfma_f32_16x16x32_bf16(kf0, qf[0], z, 0, 0, 0);
      z = __builtin_amdgcn_mfma_f32_16x16x32_bf16(kf1, qf[1], z, 0, 0, 0);
      sa[c] = z;
    }
    if (diag) {
      const int ql = wid * 16 + l15;
      #pragma unroll
      for (int c = 0; c < 4; ++c)
        #pragma unroll
        for (int r = 0; r < 4; ++r)
          if (((c >> 1) << 5) + (lg << 3) + ((c & 1) << 2) + r > ql) sa[c][r] = NEGBIG;
    }
    float pm = sa[0][0];
    #pragma unroll
    for (int c = 0; c < 4; ++c)
      #pragma unroll
      for (int r = 0; r < 4; ++r) pm = fmaxf(pm, sa[c][r]);
    pm = fmaxf(pm, __shfl_xor(pm, 16));
    pm = fmaxf(pm, __shfl_xor(pm, 32));
    if (pm > m + 8.f) {  // defer-max threshold (T13)
      const float sc = exp2f((m - pm) * LOG2E);
      l *= sc;
      #pragma unroll
      for (int dt = 0; dt < 4; ++dt) cx[dt] *= sc;
      m = pm;
    }
    float rs = 0.f;
    #pragma unroll
    for (int c = 0; c < 4; ++c)
      #pragma unroll
      for (int r = 0; r < 4; ++r) {
        const float p = exp2f((sa[c][r] - m) * LOG2E);
        sa[c][r] = p;
        rs += p;
      }
    rs += __shfl_xor(rs, 16);
    rs += __shfl_xor(rs, 32);
    l += rs;
    short8 pf[2];
    #pragma unroll
    for (int kk = 0; kk < 2; ++kk)
      #pragma unroll
      for (int jj = 0; jj < 8; ++jj)
        pf[kk][jj] = f2bf(sa[kk * 2 + (jj >> 2)][jj & 3]);
    #pragma unroll
    for (int kk = 0; kk < 2; ++kk)
      #pragma unroll
      for (int dt = 0; dt < 4; ++dt) {
        const short8 vf = *(const short8*)((char*)Vt + vt_byte(kk * 4 + lg, dt * 16 + l15, 0));
        cx[dt] = __builtin_amdgcn_mfma_f32_16x16x32_bf16(vf, pf[kk], cx[dt], 0, 0, 0);
      }
  };

  for (int j = 0; j <= qtB; ++j) {
    __syncthreads();
    {  // K stage via global_load_lds into permuted-linear layout
      const size_t rowbase = (size_t)(b * S + j * 64 + kkey) * D + h * DK;
      #pragma unroll
      for (int it = 0; it < 2; ++it) {
        const int dc = wid * 2 + it;
        gll16(&Kb[rowbase + dc * 8], (char*)Ks + dc * 1024);
      }
    }
    {  // V stage: transposed + swizzled, packed b32 writes
      const size_t vb0 = (size_t)(b * S + j * 64 + 2 * vu) * D + h * DK + ve * 8;
      const short8 va = *(const short8*)&Vb[vb0];
      const short8 vb2 = *(const short8*)&Vb[vb0 + D];
      const int kc = vu >> 2, ksb = (vu & 3) * 2;
      #pragma unroll
      for (int i = 0; i < 8; ++i) {
        const unsigned w = (unsigned)(unsigned short)va[i] | ((unsigned)(unsigned short)vb2[i] << 16);
        *(unsigned*)((char*)Vt + vt_byte(kc, ve * 8 + i, ksb)) = w;
      }
    }
    __syncthreads();
    tile(qfB, mB, lB, cB, j == qtB);
    if (j <= qtA) tile(qfA, mA, lA, cA, j == qtA);
  }

  auto epi = [&](float l, const f32x4* cx, int qt) {
    const int qg = qt * 64 + wid * 16 + l15;
    const int mq = maskp[b * S + qg];
    const float inv = 1.0f / l;
    short* orow = &ctxb[(size_t)(b * S + qg) * D + h * DK];
    const float* vmb = &vmean[(size_t)b * D + h * DK];
    #pragma unroll
    for (int dt = 0; dt < 4; ++dt)
      #pragma unroll
      for (int p2 = 0; p2 < 2; ++p2) {
        const int d = dt * 16 + 4 * lg + p2 * 2;
        const float v0 = mq ? vmb[d]     : cx[dt][p2 * 2] * inv;
        const float v1 = mq ? vmb[d + 1] : cx[dt][p2 * 2 + 1] * inv;
        *(unsigned*)&orow[d] = pack2bf(v0, v1);
      }
  };
  epi(lA, cA, qtA);
  epi(lB, cB, qtB);
}

extern "C" void kernel_launch(void* const* d_in, const int* in_sizes, int n_in,
                              void* d_out, int out_size, void* d_ws, size_t ws_size,
                              hipStream_t stream) {
  (void)in_sizes; (void)n_in; (void)out_size; (void)ws_size;
  const float* x   = (const float*)d_in[0];
  const float* enc = (const float*)d_in[1];
  const int*   msk = (const int*)d_in[2];
  const float* WQ  = (const float*)d_in[3];
  const float* WK  = (const float*)d_in[4];
  const float* WV  = (const float*)d_in[5];
  const float* WO  = (const float*)d_in[6];
  float* out = (float*)d_out;

  char* ws = (char*)d_ws;
  const size_t MB = 1u << 20;
  short* xb    = (short*)(ws + 0);          // 8 MB  (reused as ctxb)
  short* encb  = (short*)(ws + 8 * MB);     // 8 MB
  short* Qb    = (short*)(ws + 16 * MB);    // 8 MB
  short* Kb    = (short*)(ws + 24 * MB);    // 8 MB
  short* Vb    = (short*)(ws + 32 * MB);    // 8 MB
  short* WQt   = (short*)(ws + 40 * MB);
  short* WKt   = (short*)(ws + 42 * MB);
  short* WVt   = (short*)(ws + 44 * MB);
  short* WOt   = (short*)(ws + 46 * MB);
  float* vpart = (float*)(ws + 48 * MB);
  float* vmean = (float*)(ws + 48 * MB + 131072);
  short* ctxb  = xb;

  const int n4 = M * D / 4;
  cvt_bf16_kernel<<<n4 / 256, 256, 0, stream>>>(x, xb, n4);
  cvt_bf16_kernel<<<n4 / 256, 256, 0, stream>>>(enc, encb, n4);
  dim3 tg(16, 16);
  transw_kernel<<<tg, 256, 0, stream>>>(WQ, WQt);
  transw_kernel<<<tg, 256, 0, stream>>>(WK, WKt);
  transw_kernel<<<tg, 256, 0, stream>>>(WV, WVt);
  transw_kernel<<<tg, 256, 0, stream>>>(WO, WOt);

  dim3 gg(D / 128, M / 128);  // (8, 32)
  gemm_bt_kernel<1><<<gg, 256, 0, stream>>>(xb,   WQt, Qb, D, D, 0.125f);  // Q pre-scaled by 1/sqrt(dk)
  gemm_bt_kernel<1><<<gg, 256, 0, stream>>>(encb, WKt, Kb, D, D, 1.0f);
  gemm_bt_kernel<1><<<gg, 256, 0, stream>>>(encb, WVt, Vb, D, D, 1.0f);

  vmean_part_kernel<<<dim3(D / 256, 16, B), 256, 0, stream>>>(Vb, vpart);
  vmean_final_kernel<<<dim3(D / 256, B), 256, 0, stream>>>(vpart, vmean);

  attn_kernel<<<dim3(16, H, B), 256, 0, stream>>>(Qb, Kb, Vb, msk, vmean, ctxb);

  gemm_bt_kernel<0><<<gg, 256, 0, stream>>>(ctxb, WOt, out, D, D, 1.0f);
}

// Round 3
// 189.326 us; speedup vs baseline: 1.5914x; 1.3142x over previous
//
#include <hip/hip_runtime.h>
#include <hip/hip_bf16.h>

constexpr int B = 2, S = 2048, D = 1024, H = 16, DK = 64;
constexpr int M = B * S;
constexpr float LOG2E = 1.44269504088896f;
constexpr float NEGBIG = -3.0e38f;
constexpr float QSCALE = 0.125f * LOG2E;  // 1/sqrt(dk) * log2(e), folded into Q

using short8 = __attribute__((ext_vector_type(8))) short;
using short4v = __attribute__((ext_vector_type(4))) short;
using f32x4 = __attribute__((ext_vector_type(4))) float;

#define GLOBAL_AS __attribute__((address_space(1)))
#define LDS_AS __attribute__((address_space(3)))

__device__ __forceinline__ void gll16(const void* g, void* l) {
  __builtin_amdgcn_global_load_lds((const GLOBAL_AS void*)g, (LDS_AS void*)l, 16, 0, 0);
}

__device__ __forceinline__ short f2bf(float f) {
  __hip_bfloat16 h = __float2bfloat16(f);  // RNE; compiler pairs into v_cvt_pk_bf16_f32
  short s;
  __builtin_memcpy(&s, &h, 2);
  return s;
}
__device__ __forceinline__ float bf2f(short s) {
  __hip_bfloat16 h;
  __builtin_memcpy(&h, &s, 2);
  return __bfloat162float(h);
}
__device__ __forceinline__ unsigned pack2bf(float a, float b) {
  return (unsigned)(unsigned short)f2bf(a) | ((unsigned)(unsigned short)f2bf(b) << 16);
}

// ---- fp32 -> bf16 convert, x and enc fused via blockIdx.y ----
__global__ __launch_bounds__(256) void cvt_bf16_kernel(const float* __restrict__ x,
                                                       const float* __restrict__ enc,
                                                       short* __restrict__ xb,
                                                       short* __restrict__ encb) {
  const int i = blockIdx.x * 256 + threadIdx.x;
  const float4 v = ((const float4*)(blockIdx.y ? enc : x))[i];
  short4v o;
  o[0] = f2bf(v.x); o[1] = f2bf(v.y); o[2] = f2bf(v.z); o[3] = f2bf(v.w);
  ((short4v*)(blockIdx.y ? encb : xb))[i] = o;
}

// ---- weight transpose + convert, all 4 weights fused via blockIdx.z ----
__global__ __launch_bounds__(256) void transw_kernel(const float* __restrict__ W0,
                                                     const float* __restrict__ W1,
                                                     const float* __restrict__ W2,
                                                     const float* __restrict__ W3,
                                                     short* __restrict__ Wt) {
  __shared__ float t[64][65];
  const int z = blockIdx.z;
  const float* W = z == 0 ? W0 : z == 1 ? W1 : z == 2 ? W2 : W3;
  short* dst = Wt + (size_t)z * D * D;
  const int k0 = blockIdx.y * 64, n0 = blockIdx.x * 64;
  const int lx = threadIdx.x & 63, ly = threadIdx.x >> 6;
  #pragma unroll
  for (int r = 0; r < 64; r += 4)
    t[r + ly][lx] = W[(size_t)(k0 + r + ly) * D + n0 + lx];
  __syncthreads();
  #pragma unroll
  for (int r = 0; r < 64; r += 4)
    dst[(size_t)(n0 + r + ly) * D + k0 + lx] = f2bf(t[lx][r + ly]);
}

// ---- bf16 GEMM, 128x128 tile, BK=32, double-buffered 2-phase prefetch ----
// QKV=1: blockIdx.z selects {Q: xb@WQt (scaled), K: encb@WKt, V: encb@WVt}, bf16 out.
// QKV=0: single GEMM A0 @ Wts, fp32 out.
template <int QKV>
__global__ __launch_bounds__(256) void gemm_kernel(const short* __restrict__ A0,
                                                   const short* __restrict__ A1,
                                                   const short* __restrict__ Wts,
                                                   void* __restrict__ Cv) {
  __shared__ short As[2][4][128][8];  // [buf][k-chunk of 8][row][8]
  __shared__ short Bs[2][4][128][8];
  const int z = QKV ? blockIdx.z : 0;
  const short* __restrict__ A = (QKV && z) ? A1 : A0;
  const short* __restrict__ Bt = Wts + (size_t)z * D * D;
  const float oscale = (QKV && z == 0) ? QSCALE : 1.0f;

  const int tid = threadIdx.x;
  const int lane = tid & 63, wid = tid >> 6;
  const int l15 = lane & 15, lg = lane >> 4;
  const int row0 = blockIdx.y * 128, col0 = blockIdx.x * 128;
  const int wm = wid >> 1, wn = wid & 1;
  f32x4 acc[4][4] = {};

  auto stage = [&](int k0, int nb) {
    #pragma unroll
    for (int it = 0; it < 2; ++it) {
      const int t = tid + it * 256;
      const int row = t & 127, kc2 = t >> 7;  // wave-uniform kc2
      gll16(&A[(size_t)(row0 + row) * D + k0 + kc2 * 8],
            (char*)As + nb * 8192 + (wid * 64 + it * 256) * 16);
      gll16(&Bt[(size_t)(col0 + row) * D + k0 + kc2 * 8],
            (char*)Bs + nb * 8192 + (wid * 64 + it * 256) * 16);
    }
  };

  stage(0, 0);
  __syncthreads();
  int cur = 0;
  for (int t = 0; t < D / 32; ++t) {
    if (t < D / 32 - 1) stage((t + 1) * 32, cur ^ 1);  // issue next tile's loads early
    short8 af[4], bfr[4];
    #pragma unroll
    for (int m = 0; m < 4; ++m) af[m] = *(const short8*)&As[cur][lg][wm * 64 + m * 16 + l15][0];
    #pragma unroll
    for (int n = 0; n < 4; ++n) bfr[n] = *(const short8*)&Bs[cur][lg][wn * 64 + n * 16 + l15][0];
    #pragma unroll
    for (int m = 0; m < 4; ++m)
      #pragma unroll
      for (int n = 0; n < 4; ++n)
        acc[m][n] = __builtin_amdgcn_mfma_f32_16x16x32_bf16(af[m], bfr[n], acc[m][n], 0, 0, 0);
    __syncthreads();  // single drain+barrier per K-step
    cur ^= 1;
  }
  #pragma unroll
  for (int m = 0; m < 4; ++m) {
    #pragma unroll
    for (int r = 0; r < 4; ++r) {
      const int row = row0 + wm * 64 + m * 16 + 4 * lg + r;
      #pragma unroll
      for (int n = 0; n < 4; ++n) {
        const int col = col0 + wn * 64 + n * 16 + l15;
        if (QKV)
          ((short*)Cv)[(size_t)z * M * D + (size_t)row * D + col] = f2bf(acc[m][n][r] * oscale);
        else
          ((float*)Cv)[(size_t)row * D + col] = acc[m][n][r];
      }
    }
  }
}

// ---- V column means (for padding-masked query rows) ----
__global__ __launch_bounds__(256) void vmean_part_kernel(const short* __restrict__ Vb,
                                                         float* __restrict__ part) {
  const int d = blockIdx.x * 256 + threadIdx.x;
  const int c = blockIdx.y;
  const int b = blockIdx.z;
  float s = 0.f;
  for (int i = 0; i < S / 16; ++i)
    s += bf2f(Vb[(size_t)(b * S + c * (S / 16) + i) * D + d]);
  part[((size_t)b * 16 + c) * D + d] = s;
}
__global__ __launch_bounds__(256) void vmean_final_kernel(const float* __restrict__ part,
                                                          float* __restrict__ vmean) {
  const int d = blockIdx.x * 256 + threadIdx.x;
  const int b = blockIdx.y;
  float s = 0.f;
  #pragma unroll
  for (int c = 0; c < 16; ++c) s += part[((size_t)b * 16 + c) * D + d];
  vmean[(size_t)b * D + d] = s * (1.0f / S);
}

// key permutation: QK chunk c, MFMA row i -> key
__device__ __forceinline__ int keyof(int c, int i) {
  return ((c >> 1) << 5) + ((i >> 2) << 3) + ((c & 1) << 2) + (i & 3);
}
// swizzled Vt byte address within one 8KB buffer: Vt[kc][d][ksb] = V[kc*8+ksb][d]
__device__ __forceinline__ int vt_byte(int kc, int d, int ksb) {
  return kc * 1024 + ((d ^ (kc & 7)) << 4) + ksb * 2;
}

// ---- causal flash attention: paired q-tiles, swapped QK^T, P in regs, K/V dbuf ----
// grid = (H, 16 pairs, B): blocks sharing (b,h) have linear-id stride 16 -> same XCD.
__global__ __launch_bounds__(256) void attn_kernel(const short* __restrict__ Qb,
                                                   const short* __restrict__ Kb,
                                                   const short* __restrict__ Vb,
                                                   const int* __restrict__ maskp,
                                                   const float* __restrict__ vmean,
                                                   short* __restrict__ ctxb) {
  __shared__ short KsBuf[2][4096];  // 8KB each: [dc][c][i][8] = K[keyof(c,i)][dc*8+j]
  __shared__ short VtBuf[2][4096];  // 8KB each, swizzled (vt_byte)
  const int h = blockIdx.x, iblk = blockIdx.y, b = blockIdx.z;
  const int qtA = iblk, qtB = 31 - iblk;
  const int tid = threadIdx.x, lane = tid & 63, wid = tid >> 6;
  const int l15 = lane & 15, lg = lane >> 4;

  short8 qfA[2], qfB[2];
  {
    const size_t oA = (size_t)(b * S + qtA * 64 + wid * 16 + l15) * D + h * DK;
    const size_t oB = (size_t)(b * S + qtB * 64 + wid * 16 + l15) * D + h * DK;
    qfA[0] = *(const short8*)&Qb[oA + lg * 8];
    qfA[1] = *(const short8*)&Qb[oA + 32 + lg * 8];
    qfB[0] = *(const short8*)&Qb[oB + lg * 8];
    qfB[1] = *(const short8*)&Qb[oB + 32 + lg * 8];
  }
  float mA = NEGBIG, lA = 0.f, mB = NEGBIG, lB = 0.f;
  f32x4 cA[4] = {}, cB[4] = {};

  const int kkey = keyof(lane >> 4, lane & 15);  // per-lane K staging key (pre-swizzled src)
  const int vu = tid & 31, ve = tid >> 5;        // V staging map

  auto stageK = [&](int j, int nb) {
    const size_t rowbase = (size_t)(b * S + j * 64 + kkey) * D + h * DK;
    #pragma unroll
    for (int it = 0; it < 2; ++it) {
      const int dc = wid * 2 + it;
      gll16(&Kb[rowbase + dc * 8], (char*)KsBuf + nb * 8192 + dc * 1024);
    }
  };
  auto loadV = [&](int j, short8& va, short8& vb2) {
    const size_t vb0 = (size_t)(b * S + j * 64 + 2 * vu) * D + h * DK + ve * 8;
    va = *(const short8*)&Vb[vb0];
    vb2 = *(const short8*)&Vb[vb0 + D];
  };
  auto writeV = [&](int nb, const short8& va, const short8& vb2) {
    const int kc = vu >> 2, ksb = (vu & 3) * 2;
    #pragma unroll
    for (int i = 0; i < 8; ++i) {
      const unsigned w = (unsigned)(unsigned short)va[i] | ((unsigned)(unsigned short)vb2[i] << 16);
      *(unsigned*)((char*)VtBuf + nb * 8192 + vt_byte(kc, ve * 8 + i, ksb)) = w;
    }
  };

  auto tile = [&](const short8* qf, float& m, float& l, f32x4* cx, bool diag, int nb) {
    const char* ksb_ = (const char*)KsBuf + nb * 8192;
    const char* vtb_ = (const char*)VtBuf + nb * 8192;
    f32x4 sa[4];
    __builtin_amdgcn_s_setprio(1);
    #pragma unroll
    for (int c = 0; c < 4; ++c) {
      const short8 kf0 = *(const short8*)(ksb_ + lg * 1024 + c * 256 + l15 * 16);
      const short8 kf1 = *(const short8*)(ksb_ + (4 + lg) * 1024 + c * 256 + l15 * 16);
      f32x4 zz = {0.f, 0.f, 0.f, 0.f};
      zz = __builtin_amdgcn_mfma_f32_16x16x32_bf16(kf0, qf[0], zz, 0, 0, 0);
      zz = __builtin_amdgcn_mfma_f32_16x16x32_bf16(kf1, qf[1], zz, 0, 0, 0);
      sa[c] = zz;
    }
    __builtin_amdgcn_s_setprio(0);
    if (diag) {
      const int ql = wid * 16 + l15;
      #pragma unroll
      for (int c = 0; c < 4; ++c)
        #pragma unroll
        for (int r = 0; r < 4; ++r)
          if (((c >> 1) << 5) + (lg << 3) + ((c & 1) << 2) + r > ql) sa[c][r] = NEGBIG;
    }
    float pm = sa[0][0];
    #pragma unroll
    for (int c = 0; c < 4; ++c)
      #pragma unroll
      for (int r = 0; r < 4; ++r) pm = fmaxf(pm, sa[c][r]);
    pm = fmaxf(pm, __shfl_xor(pm, 16));
    pm = fmaxf(pm, __shfl_xor(pm, 32));
    if (pm > m + 8.f) {  // defer-max (T13); scores already in log2 units
      const float sc = exp2f(m - pm);
      l *= sc;
      #pragma unroll
      for (int dt = 0; dt < 4; ++dt) cx[dt] *= sc;
      m = pm;
    }
    float rs = 0.f;
    #pragma unroll
    for (int c = 0; c < 4; ++c)
      #pragma unroll
      for (int r = 0; r < 4; ++r) {
        const float p = exp2f(sa[c][r] - m);
        sa[c][r] = p;
        rs += p;
      }
    rs += __shfl_xor(rs, 16);
    rs += __shfl_xor(rs, 32);
    l += rs;
    short8 pf[2];
    #pragma unroll
    for (int kk = 0; kk < 2; ++kk)
      #pragma unroll
      for (int jj = 0; jj < 8; ++jj)
        pf[kk][jj] = f2bf(sa[kk * 2 + (jj >> 2)][jj & 3]);
    __builtin_amdgcn_s_setprio(1);
    #pragma unroll
    for (int kk = 0; kk < 2; ++kk)
      #pragma unroll
      for (int dt = 0; dt < 4; ++dt) {
        const short8 vf = *(const short8*)(vtb_ + vt_byte(kk * 4 + lg, dt * 16 + l15, 0));
        cx[dt] = __builtin_amdgcn_mfma_f32_16x16x32_bf16(vf, pf[kk], cx[dt], 0, 0, 0);
      }
    __builtin_amdgcn_s_setprio(0);
  };

  {  // prologue: stage tile 0 into buf 0
    short8 va, vb2;
    stageK(0, 0);
    loadV(0, va, vb2);
    writeV(0, va, vb2);
  }
  __syncthreads();
  int cur = 0;
  for (int j = 0; j <= qtB; ++j) {
    short8 nva, nvb;
    if (j < qtB) { stageK(j + 1, cur ^ 1); loadV(j + 1, nva, nvb); }  // issue early
    tile(qfB, mB, lB, cB, j == qtB, cur);
    if (j <= qtA) tile(qfA, mA, lA, cA, j == qtA, cur);
    if (j < qtB) writeV(cur ^ 1, nva, nvb);  // write late (T14)
    __syncthreads();
    cur ^= 1;
  }

  auto epi = [&](float l, const f32x4* cx, int qt) {
    const int qg = qt * 64 + wid * 16 + l15;
    const int mq = maskp[b * S + qg];
    const float inv = 1.0f / l;
    short* orow = &ctxb[(size_t)(b * S + qg) * D + h * DK];
    const float* vmb = &vmean[(size_t)b * D + h * DK];
    #pragma unroll
    for (int dt = 0; dt < 4; ++dt)
      #pragma unroll
      for (int p2 = 0; p2 < 2; ++p2) {
        const int d = dt * 16 + 4 * lg + p2 * 2;
        const float v0 = mq ? vmb[d]     : cx[dt][p2 * 2] * inv;
        const float v1 = mq ? vmb[d + 1] : cx[dt][p2 * 2 + 1] * inv;
        *(unsigned*)&orow[d] = pack2bf(v0, v1);
      }
  };
  epi(lA, cA, qtA);
  epi(lB, cB, qtB);
}

extern "C" void kernel_launch(void* const* d_in, const int* in_sizes, int n_in,
                              void* d_out, int out_size, void* d_ws, size_t ws_size,
                              hipStream_t stream) {
  (void)in_sizes; (void)n_in; (void)out_size; (void)ws_size;
  const float* x   = (const float*)d_in[0];
  const float* enc = (const float*)d_in[1];
  const int*   msk = (const int*)d_in[2];
  const float* WQ  = (const float*)d_in[3];
  const float* WK  = (const float*)d_in[4];
  const float* WV  = (const float*)d_in[5];
  const float* WO  = (const float*)d_in[6];
  float* out = (float*)d_out;

  char* ws = (char*)d_ws;
  const size_t MB = 1u << 20;
  short* xb    = (short*)(ws + 0);          // 8 MB  (reused as ctxb)
  short* encb  = (short*)(ws + 8 * MB);     // 8 MB
  short* Qb    = (short*)(ws + 16 * MB);    // 8 MB each; Q,K,V contiguous
  short* WQt   = (short*)(ws + 40 * MB);    // 2 MB each; WQ,WK,WV,WO contiguous
  float* vpart = (float*)(ws + 48 * MB);
  float* vmean = (float*)(ws + 48 * MB + 131072);
  short* Kb    = Qb + (size_t)M * D;
  short* Vb    = Kb + (size_t)M * D;
  short* WOt   = WQt + (size_t)3 * D * D;
  short* ctxb  = xb;

  cvt_bf16_kernel<<<dim3(M * D / 4 / 256, 2), 256, 0, stream>>>(x, enc, xb, encb);
  transw_kernel<<<dim3(16, 16, 4), 256, 0, stream>>>(WQ, WK, WV, WO, WQt);

  gemm_kernel<1><<<dim3(D / 128, M / 128, 3), 256, 0, stream>>>(xb, encb, WQt, Qb);

  vmean_part_kernel<<<dim3(D / 256, 16, B), 256, 0, stream>>>(Vb, vpart);
  vmean_final_kernel<<<dim3(D / 256, B), 256, 0, stream>>>(vpart, vmean);

  attn_kernel<<<dim3(H, 16, B), 256, 0, stream>>>(Qb, Kb, Vb, msk, vmean, ctxb);

  gemm_kernel<0><<<dim3(D / 128, M / 128, 1), 256, 0, stream>>>(ctxb, nullptr, WOt, out);
}

// Round 4
// 182.974 us; speedup vs baseline: 1.6466x; 1.0347x over previous
//
#include <hip/hip_runtime.h>
#include <hip/hip_bf16.h>

constexpr int B = 2, S = 2048, D = 1024, H = 16, DK = 64;
constexpr int M = B * S;
constexpr float LOG2E = 1.44269504088896f;
constexpr float NEGBIG = -3.0e38f;
constexpr float QSCALE = 0.125f * LOG2E;  // 1/sqrt(dk) * log2(e), folded into Q

using short8 = __attribute__((ext_vector_type(8))) short;
using short4v = __attribute__((ext_vector_type(4))) short;
using f32x4 = __attribute__((ext_vector_type(4))) float;

#define GLOBAL_AS __attribute__((address_space(1)))
#define LDS_AS __attribute__((address_space(3)))

__device__ __forceinline__ void gll16(const void* g, void* l) {
  __builtin_amdgcn_global_load_lds((const GLOBAL_AS void*)g, (LDS_AS void*)l, 16, 0, 0);
}

__device__ __forceinline__ short f2bf(float f) {
  __hip_bfloat16 h = __float2bfloat16(f);
  short s;
  __builtin_memcpy(&s, &h, 2);
  return s;
}
__device__ __forceinline__ float bf2f(short s) {
  __hip_bfloat16 h;
  __builtin_memcpy(&h, &s, 2);
  return __bfloat162float(h);
}
__device__ __forceinline__ unsigned pack2bf(float a, float b) {
  return (unsigned)(unsigned short)f2bf(a) | ((unsigned)(unsigned short)f2bf(b) << 16);
}

// ---- fused prep: fp32->bf16 convert (blocks 0..8191) + weight transpose (8192..9215) ----
__global__ __launch_bounds__(256) void prep_kernel(const float* __restrict__ x,
                                                   const float* __restrict__ enc,
                                                   const float* __restrict__ W0,
                                                   const float* __restrict__ W1,
                                                   const float* __restrict__ W2,
                                                   const float* __restrict__ W3,
                                                   short* __restrict__ xb,
                                                   short* __restrict__ encb,
                                                   short* __restrict__ Wt) {
  __shared__ float t[64][65];
  const int bx = blockIdx.x;
  if (bx < 8192) {
    const float4* src = (const float4*)((bx & 4096) ? enc : x);
    short4v* dst = (short4v*)((bx & 4096) ? encb : xb);
    const int i = (bx & 4095) * 256 + threadIdx.x;
    const float4 v = src[i];
    short4v o;
    o[0] = f2bf(v.x); o[1] = f2bf(v.y); o[2] = f2bf(v.z); o[3] = f2bf(v.w);
    dst[i] = o;
  } else {
    const int idx = bx - 8192;
    const int z = idx >> 8, rem = idx & 255;
    const float* W = z == 0 ? W0 : z == 1 ? W1 : z == 2 ? W2 : W3;
    short* dstw = Wt + (size_t)z * D * D;
    const int n0 = (rem & 15) * 64, k0 = (rem >> 4) * 64;
    const int lx = threadIdx.x & 63, ly = threadIdx.x >> 6;
    #pragma unroll
    for (int r = 0; r < 64; r += 4)
      t[r + ly][lx] = W[(size_t)(k0 + r + ly) * D + n0 + lx];
    __syncthreads();
    #pragma unroll
    for (int r = 0; r < 64; r += 4)
      dstw[(size_t)(n0 + r + ly) * D + k0 + lx] = f2bf(t[lx][r + ly]);
  }
}

// ---- QKV bf16 GEMM, 128x128 tile, BK=32, dbuf 2-phase; V-block epilogue folds column sums ----
__global__ __launch_bounds__(256) void gemm_qkv_kernel(const short* __restrict__ A0,
                                                       const short* __restrict__ A1,
                                                       const short* __restrict__ Wts,
                                                       short* __restrict__ Cv,
                                                       float* __restrict__ vsum) {
  __shared__ short As[2][4][128][8];
  __shared__ short Bs[2][4][128][8];
  const int z = blockIdx.z;
  const short* __restrict__ A = z ? A1 : A0;
  const short* __restrict__ Bt = Wts + (size_t)z * D * D;
  const float oscale = (z == 0) ? QSCALE : 1.0f;

  const int tid = threadIdx.x;
  const int lane = tid & 63, wid = tid >> 6;
  const int l15 = lane & 15, lg = lane >> 4;
  const int row0 = blockIdx.y * 128, col0 = blockIdx.x * 128;
  const int wm = wid >> 1, wn = wid & 1;
  f32x4 acc[4][4] = {};

  auto stage = [&](int k0, int nb) {
    #pragma unroll
    for (int it = 0; it < 2; ++it) {
      const int c = tid + it * 256;
      const int row = c & 127, kc2 = c >> 7;
      gll16(&A[(size_t)(row0 + row) * D + k0 + kc2 * 8],
            (char*)As + nb * 8192 + (wid * 64 + it * 256) * 16);
      gll16(&Bt[(size_t)(col0 + row) * D + k0 + kc2 * 8],
            (char*)Bs + nb * 8192 + (wid * 64 + it * 256) * 16);
    }
  };

  stage(0, 0);
  __syncthreads();
  int cur = 0;
  for (int t = 0; t < D / 32; ++t) {
    if (t < D / 32 - 1) stage((t + 1) * 32, cur ^ 1);
    short8 af[4], bfr[4];
    #pragma unroll
    for (int m = 0; m < 4; ++m) af[m] = *(const short8*)&As[cur][lg][wm * 64 + m * 16 + l15][0];
    #pragma unroll
    for (int n = 0; n < 4; ++n) bfr[n] = *(const short8*)&Bs[cur][lg][wn * 64 + n * 16 + l15][0];
    #pragma unroll
    for (int m = 0; m < 4; ++m)
      #pragma unroll
      for (int n = 0; n < 4; ++n)
        acc[m][n] = __builtin_amdgcn_mfma_f32_16x16x32_bf16(af[m], bfr[n], acc[m][n], 0, 0, 0);
    __syncthreads();
    cur ^= 1;
  }
  #pragma unroll
  for (int m = 0; m < 4; ++m) {
    #pragma unroll
    for (int r = 0; r < 4; ++r) {
      const int row = row0 + wm * 64 + m * 16 + 4 * lg + r;
      #pragma unroll
      for (int n = 0; n < 4; ++n) {
        const int col = col0 + wn * 64 + n * 16 + l15;
        Cv[(size_t)z * M * D + (size_t)row * D + col] = f2bf(acc[m][n][r] * oscale);
      }
    }
  }
  if (z == 2) {  // V-block: fold per-column sums (for masked-row mean(V))
    const int bidx = row0 >> 11;
    #pragma unroll
    for (int n = 0; n < 4; ++n) {
      float s = 0.f;
      #pragma unroll
      for (int m = 0; m < 4; ++m)
        s += acc[m][n][0] + acc[m][n][1] + acc[m][n][2] + acc[m][n][3];
      s += __shfl_xor(s, 16);
      s += __shfl_xor(s, 32);
      if (lg == 0) atomicAdd(&vsum[(size_t)bidx * D + col0 + wn * 64 + n * 16 + l15], s);
    }
  }
}

// ---- O-projection GEMM: 128x64 tile (512 blocks = 2/CU), fp32 out ----
__global__ __launch_bounds__(256) void gemmO_kernel(const short* __restrict__ A,
                                                    const short* __restrict__ Bt,
                                                    float* __restrict__ C) {
  __shared__ short As[2][4][128][8];  // 8KB x2
  __shared__ short Bs[2][4][64][8];   // 4KB x2
  const int tid = threadIdx.x;
  const int lane = tid & 63, wid = tid >> 6;
  const int l15 = lane & 15, lg = lane >> 4;
  const int col0 = blockIdx.x * 64, row0 = blockIdx.y * 128;
  const int wm = wid >> 1, wn = wid & 1;
  f32x4 acc[4][2] = {};

  auto stage = [&](int k0, int nb) {
    #pragma unroll
    for (int it = 0; it < 2; ++it) {
      const int c = tid + it * 256;
      const int row = c & 127, kc2 = c >> 7;
      gll16(&A[(size_t)(row0 + row) * D + k0 + kc2 * 8],
            (char*)As + nb * 8192 + (wid * 64 + it * 256) * 16);
    }
    gll16(&Bt[(size_t)(col0 + lane) * D + k0 + wid * 8],
          (char*)Bs + nb * 4096 + wid * 1024);
  };

  stage(0, 0);
  __syncthreads();
  int cur = 0;
  for (int t = 0; t < D / 32; ++t) {
    if (t < D / 32 - 1) stage((t + 1) * 32, cur ^ 1);
    short8 af[4], bfr[2];
    #pragma unroll
    for (int m = 0; m < 4; ++m) af[m] = *(const short8*)&As[cur][lg][wm * 64 + m * 16 + l15][0];
    #pragma unroll
    for (int n = 0; n < 2; ++n) bfr[n] = *(const short8*)&Bs[cur][lg][wn * 32 + n * 16 + l15][0];
    #pragma unroll
    for (int m = 0; m < 4; ++m)
      #pragma unroll
      for (int n = 0; n < 2; ++n)
        acc[m][n] = __builtin_amdgcn_mfma_f32_16x16x32_bf16(af[m], bfr[n], acc[m][n], 0, 0, 0);
    __syncthreads();
    cur ^= 1;
  }
  #pragma unroll
  for (int m = 0; m < 4; ++m)
    #pragma unroll
    for (int r = 0; r < 4; ++r) {
      const int row = row0 + wm * 64 + m * 16 + 4 * lg + r;
      #pragma unroll
      for (int n = 0; n < 2; ++n)
        C[(size_t)row * D + col0 + wn * 32 + n * 16 + l15] = acc[m][n][r];
    }
}

// key permutation: QK chunk c, MFMA row i -> key
__device__ __forceinline__ int keyof(int c, int i) {
  return ((c >> 1) << 5) + ((i >> 2) << 3) + ((c & 1) << 2) + (i & 3);
}
// swizzled Vt byte address within one 8KB buffer: Vt[kc][d][ksb] = V[kc*8+ksb][d]
__device__ __forceinline__ int vt_byte(int kc, int d, int ksb) {
  return kc * 1024 + ((d ^ (kc & 7)) << 4) + ksb * 2;
}

// ---- causal flash attention: 512-thr blocks, wave-split pairs (waves 0-3: tile i,
// waves 4-7: tile 31-i), swapped QK^T, P in regs, K/V dbuf, co-staged by all 8 waves.
// grid = (H, 16 pairs, B): blocks sharing (b,h) have linear-id stride 16 -> same XCD.
__global__ __launch_bounds__(512, 4) void attn_kernel(const short* __restrict__ Qb,
                                                      const short* __restrict__ Kb,
                                                      const short* __restrict__ Vb,
                                                      const int* __restrict__ maskp,
                                                      const float* __restrict__ vsum,
                                                      short* __restrict__ ctxb) {
  __shared__ short KsBuf[2][4096];  // 8KB each: [dc][c][i][8] = K[keyof(c,i)][dc*8+j]
  __shared__ short VtBuf[2][4096];  // 8KB each, swizzled (vt_byte)
  const int h = blockIdx.x, iblk = blockIdx.y, b = blockIdx.z;
  const int qtA = iblk, qtB = 31 - iblk;
  const int tid = threadIdx.x, lane = tid & 63, wid = tid >> 6;
  const int grp = wid >> 2, wq = wid & 3;
  const int qt = grp ? qtB : qtA;
  const int l15 = lane & 15, lg = lane >> 4;

  short8 qf[2];
  {
    const size_t o = (size_t)(b * S + qt * 64 + wq * 16 + l15) * D + h * DK;
    qf[0] = *(const short8*)&Qb[o + lg * 8];
    qf[1] = *(const short8*)&Qb[o + 32 + lg * 8];
  }
  float m = NEGBIG, l = 0.f;
  f32x4 cx[4] = {};

  const int kkey = keyof(lg, l15);               // per-lane K staging key (pre-swizzled src)
  const int vu = tid & 31, dv = tid >> 5;        // V staging: keys {2vu,2vu+1}, d-quad dv
  const int vkc = vu >> 2, vksb = (vu & 3) * 2;

  auto stageK = [&](int j, int nb) {
    gll16(&Kb[(size_t)(b * S + j * 64 + kkey) * D + h * DK + wid * 8],
          (char*)KsBuf + nb * 8192 + wid * 1024);
  };
  auto loadV = [&](int j, short4v& va, short4v& vb2) {
    const size_t vb0 = (size_t)(b * S + j * 64 + 2 * vu) * D + h * DK + dv * 4;
    va = *(const short4v*)&Vb[vb0];
    vb2 = *(const short4v*)&Vb[vb0 + D];
  };
  auto writeV = [&](int nb, const short4v& va, const short4v& vb2) {
    #pragma unroll
    for (int i = 0; i < 4; ++i) {
      const unsigned w = (unsigned)(unsigned short)va[i] | ((unsigned)(unsigned short)vb2[i] << 16);
      *(unsigned*)((char*)VtBuf + nb * 8192 + vt_byte(vkc, dv * 4 + i, vksb)) = w;
    }
  };

  auto tile = [&](bool diag, int nb) {
    const char* ksb_ = (const char*)KsBuf + nb * 8192;
    const char* vtb_ = (const char*)VtBuf + nb * 8192;
    f32x4 sa[4];
    __builtin_amdgcn_s_setprio(1);
    #pragma unroll
    for (int c = 0; c < 4; ++c) {
      const short8 kf0 = *(const short8*)(ksb_ + lg * 1024 + c * 256 + l15 * 16);
      const short8 kf1 = *(const short8*)(ksb_ + (4 + lg) * 1024 + c * 256 + l15 * 16);
      f32x4 zz = {0.f, 0.f, 0.f, 0.f};
      zz = __builtin_amdgcn_mfma_f32_16x16x32_bf16(kf0, qf[0], zz, 0, 0, 0);
      zz = __builtin_amdgcn_mfma_f32_16x16x32_bf16(kf1, qf[1], zz, 0, 0, 0);
      sa[c] = zz;
    }
    __builtin_amdgcn_s_setprio(0);
    if (diag) {
      const int ql = wq * 16 + l15;
      #pragma unroll
      for (int c = 0; c < 4; ++c)
        #pragma unroll
        for (int r = 0; r < 4; ++r)
          if (((c >> 1) << 5) + (lg << 3) + ((c & 1) << 2) + r > ql) sa[c][r] = NEGBIG;
    }
    float pm = sa[0][0];
    #pragma unroll
    for (int c = 0; c < 4; ++c)
      #pragma unroll
      for (int r = 0; r < 4; ++r) pm = fmaxf(pm, sa[c][r]);
    pm = fmaxf(pm, __shfl_xor(pm, 16));
    pm = fmaxf(pm, __shfl_xor(pm, 32));
    if (pm > m + 8.f) {  // defer-max (T13); scores in log2 units
      const float sc = exp2f(m - pm);
      l *= sc;
      #pragma unroll
      for (int dt = 0; dt < 4; ++dt) cx[dt] *= sc;
      m = pm;
    }
    float rs = 0.f;
    #pragma unroll
    for (int c = 0; c < 4; ++c)
      #pragma unroll
      for (int r = 0; r < 4; ++r) {
        const float p = exp2f(sa[c][r] - m);
        sa[c][r] = p;
        rs += p;
      }
    rs += __shfl_xor(rs, 16);
    rs += __shfl_xor(rs, 32);
    l += rs;
    short8 pf[2];
    #pragma unroll
    for (int kk = 0; kk < 2; ++kk)
      #pragma unroll
      for (int jj = 0; jj < 8; ++jj)
        pf[kk][jj] = f2bf(sa[kk * 2 + (jj >> 2)][jj & 3]);
    __builtin_amdgcn_s_setprio(1);
    #pragma unroll
    for (int kk = 0; kk < 2; ++kk)
      #pragma unroll
      for (int dt = 0; dt < 4; ++dt) {
        const short8 vf = *(const short8*)(vtb_ + vt_byte(kk * 4 + lg, dt * 16 + l15, 0));
        cx[dt] = __builtin_amdgcn_mfma_f32_16x16x32_bf16(vf, pf[kk], cx[dt], 0, 0, 0);
      }
    __builtin_amdgcn_s_setprio(0);
  };

  {  // prologue: stage tile 0 into buf 0
    short4v va, vb2;
    stageK(0, 0);
    loadV(0, va, vb2);
    writeV(0, va, vb2);
  }
  __syncthreads();
  int cur = 0;
  for (int j = 0; j <= qtB; ++j) {
    short4v nva, nvb;
    if (j < qtB) { stageK(j + 1, cur ^ 1); loadV(j + 1, nva, nvb); }  // issue early
    if (j <= qt) tile(j == qt, cur);
    if (j < qtB) writeV(cur ^ 1, nva, nvb);  // write late (T14)
    __syncthreads();
    cur ^= 1;
  }

  {  // epilogue: normalize; masked query rows -> mean(V) = vsum/S
    const int qg = qt * 64 + wq * 16 + l15;
    const int mq = maskp[b * S + qg];
    const float inv = 1.0f / l;
    constexpr float vscale = 1.0f / S;
    short* orow = &ctxb[(size_t)(b * S + qg) * D + h * DK];
    const float* vmb = &vsum[(size_t)b * D + h * DK];
    #pragma unroll
    for (int dt = 0; dt < 4; ++dt)
      #pragma unroll
      for (int p2 = 0; p2 < 2; ++p2) {
        const int d = dt * 16 + 4 * lg + p2 * 2;
        const float v0 = mq ? vmb[d] * vscale     : cx[dt][p2 * 2] * inv;
        const float v1 = mq ? vmb[d + 1] * vscale : cx[dt][p2 * 2 + 1] * inv;
        *(unsigned*)&orow[d] = pack2bf(v0, v1);
      }
  }
}

extern "C" void kernel_launch(void* const* d_in, const int* in_sizes, int n_in,
                              void* d_out, int out_size, void* d_ws, size_t ws_size,
                              hipStream_t stream) {
  (void)in_sizes; (void)n_in; (void)out_size; (void)ws_size;
  const float* x   = (const float*)d_in[0];
  const float* enc = (const float*)d_in[1];
  const int*   msk = (const int*)d_in[2];
  const float* WQ  = (const float*)d_in[3];
  const float* WK  = (const float*)d_in[4];
  const float* WV  = (const float*)d_in[5];
  const float* WO  = (const float*)d_in[6];
  float* out = (float*)d_out;

  char* ws = (char*)d_ws;
  const size_t MB = 1u << 20;
  short* xb    = (short*)(ws + 0);          // 8 MB  (reused as ctxb)
  short* encb  = (short*)(ws + 8 * MB);     // 8 MB
  short* Qb    = (short*)(ws + 16 * MB);    // 8 MB each; Q,K,V contiguous
  short* WQt   = (short*)(ws + 40 * MB);    // 2 MB each; WQ,WK,WV,WO contiguous
  float* vsum  = (float*)(ws + 48 * MB);    // 8 KB
  short* Kb    = Qb + (size_t)M * D;
  short* Vb    = Kb + (size_t)M * D;
  short* WOt   = WQt + (size_t)3 * D * D;
  short* ctxb  = xb;

  hipMemsetAsync(vsum, 0, (size_t)B * D * sizeof(float), stream);

  prep_kernel<<<dim3(9216), 256, 0, stream>>>(x, enc, WQ, WK, WV, WO, xb, encb, WQt);

  gemm_qkv_kernel<<<dim3(D / 128, M / 128, 3), 256, 0, stream>>>(xb, encb, WQt, Qb, vsum);

  attn_kernel<<<dim3(H, 16, B), 512, 0, stream>>>(Qb, Kb, Vb, msk, vsum, ctxb);

  gemmO_kernel<<<dim3(D / 64, M / 128), 256, 0, stream>>>(ctxb, WOt, out);
}

// Round 5
// 167.451 us; speedup vs baseline: 1.7992x; 1.0927x over previous
//
#include <hip/hip_runtime.h>
#include <hip/hip_bf16.h>

constexpr int B = 2, S = 2048, D = 1024, H = 16, DK = 64;
constexpr int M = B * S;
constexpr float LOG2E = 1.44269504088896f;
constexpr float NEGBIG = -3.0e38f;
constexpr float QSCALE = 0.125f * LOG2E;  // 1/sqrt(dk) * log2(e), folded into Q

using short8 = __attribute__((ext_vector_type(8))) short;
using short4v = __attribute__((ext_vector_type(4))) short;
using f32x4 = __attribute__((ext_vector_type(4))) float;

#define GLOBAL_AS __attribute__((address_space(1)))
#define LDS_AS __attribute__((address_space(3)))

__device__ __forceinline__ void gll16(const void* g, void* l) {
  __builtin_amdgcn_global_load_lds((const GLOBAL_AS void*)g, (LDS_AS void*)l, 16, 0, 0);
}

__device__ __forceinline__ short f2bf(float f) {
  __hip_bfloat16 h = __float2bfloat16(f);
  short s;
  __builtin_memcpy(&s, &h, 2);
  return s;
}
__device__ __forceinline__ unsigned pack2bf(float a, float b) {
  return (unsigned)(unsigned short)f2bf(a) | ((unsigned)(unsigned short)f2bf(b) << 16);
}

// ---- fused prep: fp32->bf16 convert (blocks 0..8191) + weight transpose (8192..9215) ----
__global__ __launch_bounds__(256) void prep_kernel(const float* __restrict__ x,
                                                   const float* __restrict__ enc,
                                                   const float* __restrict__ W0,
                                                   const float* __restrict__ W1,
                                                   const float* __restrict__ W2,
                                                   const float* __restrict__ W3,
                                                   short* __restrict__ xb,
                                                   short* __restrict__ encb,
                                                   short* __restrict__ Wt) {
  __shared__ float t[64][65];
  const int bx = blockIdx.x;
  if (bx < 8192) {
    const float4* src = (const float4*)((bx & 4096) ? enc : x);
    short4v* dst = (short4v*)((bx & 4096) ? encb : xb);
    const int i = (bx & 4095) * 256 + threadIdx.x;
    const float4 v = src[i];
    short4v o;
    o[0] = f2bf(v.x); o[1] = f2bf(v.y); o[2] = f2bf(v.z); o[3] = f2bf(v.w);
    dst[i] = o;
  } else {
    const int idx = bx - 8192;
    const int z = idx >> 8, rem = idx & 255;
    const float* W = z == 0 ? W0 : z == 1 ? W1 : z == 2 ? W2 : W3;
    short* dstw = Wt + (size_t)z * D * D;
    const int n0 = (rem & 15) * 64, k0 = (rem >> 4) * 64;
    const int lx = threadIdx.x & 63, ly = threadIdx.x >> 6;
    #pragma unroll
    for (int r = 0; r < 64; r += 4)
      t[r + ly][lx] = W[(size_t)(k0 + r + ly) * D + n0 + lx];
    __syncthreads();
    #pragma unroll
    for (int r = 0; r < 64; r += 4)
      dstw[(size_t)(n0 + r + ly) * D + k0 + lx] = f2bf(t[lx][r + ly]);
  }
}

// ---- QKV bf16 GEMM, 128x128 tile, BK=32, dbuf 2-phase; grid x=row (A-panel XCD locality) ----
__global__ __launch_bounds__(256) void gemm_qkv_kernel(const short* __restrict__ A0,
                                                       const short* __restrict__ A1,
                                                       const short* __restrict__ Wts,
                                                       short* __restrict__ Cv,
                                                       float* __restrict__ vsum) {
  __shared__ short As[2][4][128][8];
  __shared__ short Bs[2][4][128][8];
  const int z = blockIdx.z;
  const short* __restrict__ A = z ? A1 : A0;
  const short* __restrict__ Bt = Wts + (size_t)z * D * D;
  const float oscale = (z == 0) ? QSCALE : 1.0f;

  const int tid = threadIdx.x;
  const int lane = tid & 63, wid = tid >> 6;
  const int l15 = lane & 15, lg = lane >> 4;
  const int row0 = blockIdx.x * 128, col0 = blockIdx.y * 128;  // x = row: A-locality per XCD
  const int wm = wid >> 1, wn = wid & 1;
  f32x4 acc[4][4] = {};

  auto stage = [&](int k0, int nb) {
    #pragma unroll
    for (int it = 0; it < 2; ++it) {
      const int c = tid + it * 256;
      const int row = c & 127, kc2 = c >> 7;
      gll16(&A[(size_t)(row0 + row) * D + k0 + kc2 * 8],
            (char*)As + nb * 8192 + (wid * 64 + it * 256) * 16);
      gll16(&Bt[(size_t)(col0 + row) * D + k0 + kc2 * 8],
            (char*)Bs + nb * 8192 + (wid * 64 + it * 256) * 16);
    }
  };

  stage(0, 0);
  __syncthreads();
  int cur = 0;
  for (int t = 0; t < D / 32; ++t) {
    if (t < D / 32 - 1) stage((t + 1) * 32, cur ^ 1);
    short8 af[4], bfr[4];
    #pragma unroll
    for (int m = 0; m < 4; ++m) af[m] = *(const short8*)&As[cur][lg][wm * 64 + m * 16 + l15][0];
    #pragma unroll
    for (int n = 0; n < 4; ++n) bfr[n] = *(const short8*)&Bs[cur][lg][wn * 64 + n * 16 + l15][0];
    #pragma unroll
    for (int m = 0; m < 4; ++m)
      #pragma unroll
      for (int n = 0; n < 4; ++n)
        acc[m][n] = __builtin_amdgcn_mfma_f32_16x16x32_bf16(af[m], bfr[n], acc[m][n], 0, 0, 0);
    __syncthreads();
    cur ^= 1;
  }
  #pragma unroll
  for (int m = 0; m < 4; ++m) {
    #pragma unroll
    for (int r = 0; r < 4; ++r) {
      const int row = row0 + wm * 64 + m * 16 + 4 * lg + r;
      #pragma unroll
      for (int n = 0; n < 4; ++n) {
        const int col = col0 + wn * 64 + n * 16 + l15;
        Cv[(size_t)z * M * D + (size_t)row * D + col] = f2bf(acc[m][n][r] * oscale);
      }
    }
  }
  if (z == 2) {  // V-block: fold per-column sums (for masked-row mean(V))
    const int bidx = row0 >> 11;
    #pragma unroll
    for (int n = 0; n < 4; ++n) {
      float s = 0.f;
      #pragma unroll
      for (int m = 0; m < 4; ++m)
        s += acc[m][n][0] + acc[m][n][1] + acc[m][n][2] + acc[m][n][3];
      s += __shfl_xor(s, 16);
      s += __shfl_xor(s, 32);
      if (lg == 0) atomicAdd(&vsum[(size_t)bidx * D + col0 + wn * 64 + n * 16 + l15], s);
    }
  }
}

// ---- O-projection GEMM: 128x64 tile, grid x=row, fp32 out ----
__global__ __launch_bounds__(256) void gemmO_kernel(const short* __restrict__ A,
                                                    const short* __restrict__ Bt,
                                                    float* __restrict__ C) {
  __shared__ short As[2][4][128][8];  // 8KB x2
  __shared__ short Bs[2][4][64][8];   // 4KB x2
  const int tid = threadIdx.x;
  const int lane = tid & 63, wid = tid >> 6;
  const int l15 = lane & 15, lg = lane >> 4;
  const int row0 = blockIdx.x * 128, col0 = blockIdx.y * 64;
  const int wm = wid >> 1, wn = wid & 1;
  f32x4 acc[4][2] = {};

  auto stage = [&](int k0, int nb) {
    #pragma unroll
    for (int it = 0; it < 2; ++it) {
      const int c = tid + it * 256;
      const int row = c & 127, kc2 = c >> 7;
      gll16(&A[(size_t)(row0 + row) * D + k0 + kc2 * 8],
            (char*)As + nb * 8192 + (wid * 64 + it * 256) * 16);
    }
    gll16(&Bt[(size_t)(col0 + lane) * D + k0 + wid * 8],
          (char*)Bs + nb * 4096 + wid * 1024);
  };

  stage(0, 0);
  __syncthreads();
  int cur = 0;
  for (int t = 0; t < D / 32; ++t) {
    if (t < D / 32 - 1) stage((t + 1) * 32, cur ^ 1);
    short8 af[4], bfr[2];
    #pragma unroll
    for (int m = 0; m < 4; ++m) af[m] = *(const short8*)&As[cur][lg][wm * 64 + m * 16 + l15][0];
    #pragma unroll
    for (int n = 0; n < 2; ++n) bfr[n] = *(const short8*)&Bs[cur][lg][wn * 32 + n * 16 + l15][0];
    #pragma unroll
    for (int m = 0; m < 4; ++m)
      #pragma unroll
      for (int n = 0; n < 2; ++n)
        acc[m][n] = __builtin_amdgcn_mfma_f32_16x16x32_bf16(af[m], bfr[n], acc[m][n], 0, 0, 0);
    __syncthreads();
    cur ^= 1;
  }
  #pragma unroll
  for (int m = 0; m < 4; ++m)
    #pragma unroll
    for (int r = 0; r < 4; ++r) {
      const int row = row0 + wm * 64 + m * 16 + 4 * lg + r;
      #pragma unroll
      for (int n = 0; n < 2; ++n)
        C[(size_t)row * D + col0 + wn * 32 + n * 16 + l15] = acc[m][n][r];
    }
}

// key permutation: QK chunk c, MFMA row i -> key (within 64-key tile)
__device__ __forceinline__ int keyof(int c, int i) {
  return ((c >> 1) << 5) + ((i >> 2) << 3) + ((c & 1) << 2) + (i & 3);
}
// swizzled Vt byte address within one 8KB half-buffer: Vt[kc][d][ksb] = V[kc*8+ksb][d]
__device__ __forceinline__ int vt_byte(int kc, int d, int ksb) {
  return kc * 1024 + ((d ^ (kc & 7)) << 4) + ksb * 2;
}

// ---- causal flash attention: 512-thr blocks, wave-split pairs (waves 0-3: tile i,
// waves 4-7: tile 31-i), 128-key chunks (2 tiles/barrier), merged softmax, P in regs.
// grid = (H, 16 pairs, B): blocks sharing (b,h) have linear-id stride 16 -> same XCD.
__global__ __launch_bounds__(512, 4) void attn_kernel(const short* __restrict__ Qb,
                                                      const short* __restrict__ Kb,
                                                      const short* __restrict__ Vb,
                                                      const int* __restrict__ maskp,
                                                      const float* __restrict__ vsum,
                                                      short* __restrict__ ctxb) {
  __shared__ char KsBuf[2][16384];  // [buf][half*8192 + dc*1024 + c*256 + i*16]
  __shared__ char VtBuf[2][16384];  // [buf][half*8192 + vt_byte(kc,d,ksb)]
  const int h = blockIdx.x, iblk = blockIdx.y, b = blockIdx.z;
  const int qtA = iblk, qtB = 31 - iblk;
  const int tid = threadIdx.x, lane = tid & 63, wid = tid >> 6;
  const int grp = wid >> 2, wq = wid & 3;
  const int qt = grp ? qtB : qtA;
  const int l15 = lane & 15, lg = lane >> 4;

  short8 qf[2];
  {
    const size_t o = (size_t)(b * S + qt * 64 + wq * 16 + l15) * D + h * DK;
    qf[0] = *(const short8*)&Qb[o + lg * 8];
    qf[1] = *(const short8*)&Qb[o + 32 + lg * 8];
  }
  float m = NEGBIG, l = 0.f;
  f32x4 cx[4] = {};

  const int kkey = keyof(lg, l15);        // per-lane K staging key (pre-swizzled src)
  const int vu = tid & 63, dv = tid >> 6; // V staging: key pair {2vu,2vu+1}, d-octet dv
  const int vh = vu >> 5, vl = vu & 31;
  const int vkc = vl >> 2, vksb = (vl & 3) * 2;

  auto stageK = [&](int jc, int nb) {
    const size_t base = (size_t)(b * S + jc * 128 + kkey) * D + h * DK + wid * 8;
    gll16(&Kb[base], (char*)KsBuf + nb * 16384 + wid * 1024);
    gll16(&Kb[base + (size_t)64 * D], (char*)KsBuf + nb * 16384 + 8192 + wid * 1024);
  };
  auto loadV = [&](int jc, short8& va, short8& vb2) {
    const size_t vb0 = (size_t)(b * S + jc * 128 + 2 * vu) * D + h * DK + dv * 8;
    va = *(const short8*)&Vb[vb0];
    vb2 = *(const short8*)&Vb[vb0 + D];
  };
  auto writeV = [&](int nb, const short8& va, const short8& vb2) {
    char* dst = (char*)VtBuf + nb * 16384 + vh * 8192;
    #pragma unroll
    for (int i = 0; i < 8; ++i) {
      const unsigned w = (unsigned)(unsigned short)va[i] | ((unsigned)(unsigned short)vb2[i] << 16);
      *(unsigned*)(dst + vt_byte(vkc, dv * 8 + i, vksb)) = w;
    }
  };

  // one 128-key chunk: both halves' scores, ONE merged softmax, two PV steps
  auto tile_pair = [&](int nb, bool do1, bool diag0, bool diag1) {
    const char* ks0 = (const char*)KsBuf + nb * 16384;
    const char* ks1 = ks0 + 8192;
    const char* vt0 = (const char*)VtBuf + nb * 16384;
    const char* vt1 = vt0 + 8192;
    f32x4 sa0[4], sa1[4];
    #pragma unroll
    for (int c = 0; c < 4; ++c) {
      const short8 kf0 = *(const short8*)(ks0 + lg * 1024 + c * 256 + l15 * 16);
      const short8 kf1 = *(const short8*)(ks0 + (4 + lg) * 1024 + c * 256 + l15 * 16);
      f32x4 zz = {0.f, 0.f, 0.f, 0.f};
      zz = __builtin_amdgcn_mfma_f32_16x16x32_bf16(kf0, qf[0], zz, 0, 0, 0);
      zz = __builtin_amdgcn_mfma_f32_16x16x32_bf16(kf1, qf[1], zz, 0, 0, 0);
      sa0[c] = zz;
    }
    if (do1) {
      #pragma unroll
      for (int c = 0; c < 4; ++c) {
        const short8 kf0 = *(const short8*)(ks1 + lg * 1024 + c * 256 + l15 * 16);
        const short8 kf1 = *(const short8*)(ks1 + (4 + lg) * 1024 + c * 256 + l15 * 16);
        f32x4 zz = {0.f, 0.f, 0.f, 0.f};
        zz = __builtin_amdgcn_mfma_f32_16x16x32_bf16(kf0, qf[0], zz, 0, 0, 0);
        zz = __builtin_amdgcn_mfma_f32_16x16x32_bf16(kf1, qf[1], zz, 0, 0, 0);
        sa1[c] = zz;
      }
    }
    const int ql = wq * 16 + l15;
    if (diag0) {
      #pragma unroll
      for (int c = 0; c < 4; ++c)
        #pragma unroll
        for (int r = 0; r < 4; ++r)
          if (((c >> 1) << 5) + (lg << 3) + ((c & 1) << 2) + r > ql) sa0[c][r] = NEGBIG;
    }
    if (do1 && diag1) {
      #pragma unroll
      for (int c = 0; c < 4; ++c)
        #pragma unroll
        for (int r = 0; r < 4; ++r)
          if (((c >> 1) << 5) + (lg << 3) + ((c & 1) << 2) + r > ql) sa1[c][r] = NEGBIG;
    }
    float pm = sa0[0][0];
    #pragma unroll
    for (int c = 0; c < 4; ++c)
      #pragma unroll
      for (int r = 0; r < 4; ++r) pm = fmaxf(pm, sa0[c][r]);
    if (do1)
      #pragma unroll
      for (int c = 0; c < 4; ++c)
        #pragma unroll
        for (int r = 0; r < 4; ++r) pm = fmaxf(pm, sa1[c][r]);
    pm = fmaxf(pm, __shfl_xor(pm, 16));
    pm = fmaxf(pm, __shfl_xor(pm, 32));
    if (pm > m + 8.f) {  // defer-max (T13); scores in log2 units
      const float sc = exp2f(m - pm);
      l *= sc;
      #pragma unroll
      for (int dt = 0; dt < 4; ++dt) cx[dt] *= sc;
      m = pm;
    }
    float rs = 0.f;
    #pragma unroll
    for (int c = 0; c < 4; ++c)
      #pragma unroll
      for (int r = 0; r < 4; ++r) {
        const float p = exp2f(sa0[c][r] - m);
        sa0[c][r] = p;
        rs += p;
      }
    if (do1)
      #pragma unroll
      for (int c = 0; c < 4; ++c)
        #pragma unroll
        for (int r = 0; r < 4; ++r) {
          const float p = exp2f(sa1[c][r] - m);
          sa1[c][r] = p;
          rs += p;
        }
    rs += __shfl_xor(rs, 16);
    rs += __shfl_xor(rs, 32);
    l += rs;
    {
      short8 pf[2];
      #pragma unroll
      for (int kk = 0; kk < 2; ++kk)
        #pragma unroll
        for (int jj = 0; jj < 8; ++jj)
          pf[kk][jj] = f2bf(sa0[kk * 2 + (jj >> 2)][jj & 3]);
      #pragma unroll
      for (int kk = 0; kk < 2; ++kk)
        #pragma unroll
        for (int dt = 0; dt < 4; ++dt) {
          const short8 vf = *(const short8*)(vt0 + vt_byte(kk * 4 + lg, dt * 16 + l15, 0));
          cx[dt] = __builtin_amdgcn_mfma_f32_16x16x32_bf16(vf, pf[kk], cx[dt], 0, 0, 0);
        }
    }
    if (do1) {
      short8 pf[2];
      #pragma unroll
      for (int kk = 0; kk < 2; ++kk)
        #pragma unroll
        for (int jj = 0; jj < 8; ++jj)
          pf[kk][jj] = f2bf(sa1[kk * 2 + (jj >> 2)][jj & 3]);
      #pragma unroll
      for (int kk = 0; kk < 2; ++kk)
        #pragma unroll
        for (int dt = 0; dt < 4; ++dt) {
          const short8 vf = *(const short8*)(vt1 + vt_byte(kk * 4 + lg, dt * 16 + l15, 0));
          cx[dt] = __builtin_amdgcn_mfma_f32_16x16x32_bf16(vf, pf[kk], cx[dt], 0, 0, 0);
        }
    }
  };

  const int nB = (qtB >> 1) + 1;  // 128-key chunks covering tiles 0..qtB
  {  // prologue: stage chunk 0 into buf 0
    short8 va, vb2;
    stageK(0, 0);
    loadV(0, va, vb2);
    writeV(0, va, vb2);
  }
  __syncthreads();
  int cur = 0;
  for (int jc = 0; jc < nB; ++jc) {
    short8 nva, nvb;
    if (jc + 1 < nB) { stageK(jc + 1, cur ^ 1); loadV(jc + 1, nva, nvb); }  // issue early
    const int t0 = 2 * jc, t1 = 2 * jc + 1;
    if (t0 <= qt) tile_pair(cur, t1 <= qt, t0 == qt, t1 == qt);
    if (jc + 1 < nB) writeV(cur ^ 1, nva, nvb);  // write late (T14)
    __syncthreads();
    cur ^= 1;
  }

  {  // epilogue: normalize; masked query rows -> mean(V) = vsum/S
    const int qg = qt * 64 + wq * 16 + l15;
    const int mq = maskp[b * S + qg];
    const float inv = 1.0f / l;
    constexpr float vscale = 1.0f / S;
    short* orow = &ctxb[(size_t)(b * S + qg) * D + h * DK];
    const float* vmb = &vsum[(size_t)b * D + h * DK];
    #pragma unroll
    for (int dt = 0; dt < 4; ++dt)
      #pragma unroll
      for (int p2 = 0; p2 < 2; ++p2) {
        const int d = dt * 16 + 4 * lg + p2 * 2;
        const float v0 = mq ? vmb[d] * vscale     : cx[dt][p2 * 2] * inv;
        const float v1 = mq ? vmb[d + 1] * vscale : cx[dt][p2 * 2 + 1] * inv;
        *(unsigned*)&orow[d] = pack2bf(v0, v1);
      }
  }
}

extern "C" void kernel_launch(void* const* d_in, const int* in_sizes, int n_in,
                              void* d_out, int out_size, void* d_ws, size_t ws_size,
                              hipStream_t stream) {
  (void)in_sizes; (void)n_in; (void)out_size; (void)ws_size;
  const float* x   = (const float*)d_in[0];
  const float* enc = (const float*)d_in[1];
  const int*   msk = (const int*)d_in[2];
  const float* WQ  = (const float*)d_in[3];
  const float* WK  = (const float*)d_in[4];
  const float* WV  = (const float*)d_in[5];
  const float* WO  = (const float*)d_in[6];
  float* out = (float*)d_out;

  char* ws = (char*)d_ws;
  const size_t MB = 1u << 20;
  short* xb    = (short*)(ws + 0);          // 8 MB  (reused as ctxb)
  short* encb  = (short*)(ws + 8 * MB);     // 8 MB
  short* Qb    = (short*)(ws + 16 * MB);    // 8 MB each; Q,K,V contiguous
  short* WQt   = (short*)(ws + 40 * MB);    // 2 MB each; WQ,WK,WV,WO contiguous
  float* vsum  = (float*)(ws + 48 * MB);    // 8 KB
  short* Kb    = Qb + (size_t)M * D;
  short* Vb    = Kb + (size_t)M * D;
  short* WOt   = WQt + (size_t)3 * D * D;
  short* ctxb  = xb;

  hipMemsetAsync(vsum, 0, (size_t)B * D * sizeof(float), stream);

  prep_kernel<<<dim3(9216), 256, 0, stream>>>(x, enc, WQ, WK, WV, WO, xb, encb, WQt);

  gemm_qkv_kernel<<<dim3(M / 128, D / 128, 3), 256, 0, stream>>>(xb, encb, WQt, Qb, vsum);

  attn_kernel<<<dim3(H, 16, B), 512, 0, stream>>>(Qb, Kb, Vb, msk, vsum, ctxb);

  gemmO_kernel<<<dim3(M / 128, D / 64), 256, 0, stream>>>(ctxb, WOt, out);
}

// Round 6
// 166.407 us; speedup vs baseline: 1.8105x; 1.0063x over previous
//
#include <hip/hip_runtime.h>
#include <hip/hip_bf16.h>

constexpr int B = 2, S = 2048, D = 1024, H = 16, DK = 64;
constexpr int M = B * S;
constexpr float LOG2E = 1.44269504088896f;
constexpr float NEGBIG = -3.0e38f;
constexpr float QSCALE = 0.125f * LOG2E;  // 1/sqrt(dk) * log2(e), folded into Q

using short8 = __attribute__((ext_vector_type(8))) short;
using short4v = __attribute__((ext_vector_type(4))) short;
using f32x4 = __attribute__((ext_vector_type(4))) float;

#define GLOBAL_AS __attribute__((address_space(1)))
#define LDS_AS __attribute__((address_space(3)))

__device__ __forceinline__ void gll16(const void* g, void* l) {
  __builtin_amdgcn_global_load_lds((const GLOBAL_AS void*)g, (LDS_AS void*)l, 16, 0, 0);
}

__device__ __forceinline__ short f2bf(float f) {
  __hip_bfloat16 h = __float2bfloat16(f);
  short s;
  __builtin_memcpy(&s, &h, 2);
  return s;
}
__device__ __forceinline__ unsigned pack2bf(float a, float b) {
  return (unsigned)(unsigned short)f2bf(a) | ((unsigned)(unsigned short)f2bf(b) << 16);
}

// ---- fused prep: fp32->bf16 convert (blocks 0..8191) + weight transpose (8192..9215) ----
__global__ __launch_bounds__(256) void prep_kernel(const float* __restrict__ x,
                                                   const float* __restrict__ enc,
                                                   const float* __restrict__ W0,
                                                   const float* __restrict__ W1,
                                                   const float* __restrict__ W2,
                                                   const float* __restrict__ W3,
                                                   short* __restrict__ xb,
                                                   short* __restrict__ encb,
                                                   short* __restrict__ Wt) {
  __shared__ float t[64][65];
  const int bx = blockIdx.x;
  if (bx < 8192) {
    const float4* src = (const float4*)((bx & 4096) ? enc : x);
    short4v* dst = (short4v*)((bx & 4096) ? encb : xb);
    const int i = (bx & 4095) * 256 + threadIdx.x;
    const float4 v = src[i];
    short4v o;
    o[0] = f2bf(v.x); o[1] = f2bf(v.y); o[2] = f2bf(v.z); o[3] = f2bf(v.w);
    dst[i] = o;
  } else {
    const int idx = bx - 8192;
    const int z = idx >> 8, rem = idx & 255;
    const float* W = z == 0 ? W0 : z == 1 ? W1 : z == 2 ? W2 : W3;
    short* dstw = Wt + (size_t)z * D * D;
    const int n0 = (rem & 15) * 64, k0 = (rem >> 4) * 64;
    const int lx = threadIdx.x & 63, ly = threadIdx.x >> 6;
    #pragma unroll
    for (int r = 0; r < 64; r += 4)
      t[r + ly][lx] = W[(size_t)(k0 + r + ly) * D + n0 + lx];
    __syncthreads();
    #pragma unroll
    for (int r = 0; r < 64; r += 4)
      dstw[(size_t)(n0 + r + ly) * D + k0 + lx] = f2bf(t[lx][r + ly]);
  }
}

// ---- QKV bf16 GEMM, 128x128 tile, BK=32, 3-buf counted-vmcnt pipeline (T4) ----
__global__ __launch_bounds__(256) void gemm_qkv_kernel(const short* __restrict__ A0,
                                                       const short* __restrict__ A1,
                                                       const short* __restrict__ Wts,
                                                       short* __restrict__ Cv,
                                                       float* __restrict__ vsum) {
  __shared__ short As[3][4][128][8];  // 8KB per buf
  __shared__ short Bs[3][4][128][8];
  const int z = blockIdx.z;
  const short* __restrict__ A = z ? A1 : A0;
  const short* __restrict__ Bt = Wts + (size_t)z * D * D;
  const float oscale = (z == 0) ? QSCALE : 1.0f;

  const int tid = threadIdx.x;
  const int lane = tid & 63, wid = tid >> 6;
  const int l15 = lane & 15, lg = lane >> 4;
  const int row0 = blockIdx.x * 128, col0 = blockIdx.y * 128;  // x = row: A-locality per XCD
  const int wm = wid >> 1, wn = wid & 1;
  f32x4 acc[4][4] = {};
  constexpr int NSTEP = D / 32;

  auto stage = [&](int k0, int nb) {  // 4 loads per thread
    #pragma unroll
    for (int it = 0; it < 2; ++it) {
      const int c = tid + it * 256;
      const int row = c & 127, kc2 = c >> 7;
      gll16(&A[(size_t)(row0 + row) * D + k0 + kc2 * 8],
            (char*)As + nb * 8192 + (wid * 64 + it * 256) * 16);
      gll16(&Bt[(size_t)(col0 + row) * D + k0 + kc2 * 8],
            (char*)Bs + nb * 8192 + (wid * 64 + it * 256) * 16);
    }
  };

  stage(0, 0);
  stage(32, 1);
  for (int t = 0; t < NSTEP; ++t) {
    // wait for stage(t) only (stage(t+1) stays in flight), then barrier
    if (t < NSTEP - 1) asm volatile("s_waitcnt vmcnt(4)\ns_barrier" ::: "memory");
    else               asm volatile("s_waitcnt vmcnt(0)\ns_barrier" ::: "memory");
    if (t + 2 < NSTEP) stage((t + 2) * 32, (t + 2) % 3);  // after barrier: buf (t-1)%3 free
    const int cur = t % 3;
    short8 af[4], bfr[4];
    #pragma unroll
    for (int m = 0; m < 4; ++m) af[m] = *(const short8*)&As[cur][lg][wm * 64 + m * 16 + l15][0];
    #pragma unroll
    for (int n = 0; n < 4; ++n) bfr[n] = *(const short8*)&Bs[cur][lg][wn * 64 + n * 16 + l15][0];
    #pragma unroll
    for (int m = 0; m < 4; ++m)
      #pragma unroll
      for (int n = 0; n < 4; ++n)
        acc[m][n] = __builtin_amdgcn_mfma_f32_16x16x32_bf16(af[m], bfr[n], acc[m][n], 0, 0, 0);
  }
  #pragma unroll
  for (int m = 0; m < 4; ++m) {
    #pragma unroll
    for (int r = 0; r < 4; ++r) {
      const int row = row0 + wm * 64 + m * 16 + 4 * lg + r;
      #pragma unroll
      for (int n = 0; n < 4; ++n) {
        const int col = col0 + wn * 64 + n * 16 + l15;
        Cv[(size_t)z * M * D + (size_t)row * D + col] = f2bf(acc[m][n][r] * oscale);
      }
    }
  }
  if (z == 2) {  // V-block: fold per-column sums (for masked-row mean(V))
    const int bidx = row0 >> 11;
    #pragma unroll
    for (int n = 0; n < 4; ++n) {
      float s = 0.f;
      #pragma unroll
      for (int m = 0; m < 4; ++m)
        s += acc[m][n][0] + acc[m][n][1] + acc[m][n][2] + acc[m][n][3];
      s += __shfl_xor(s, 16);
      s += __shfl_xor(s, 32);
      if (lg == 0) atomicAdd(&vsum[(size_t)bidx * D + col0 + wn * 64 + n * 16 + l15], s);
    }
  }
}

// ---- O-projection GEMM: 128x64 tile, 3-buf counted-vmcnt pipeline, fp32 out ----
__global__ __launch_bounds__(256) void gemmO_kernel(const short* __restrict__ A,
                                                    const short* __restrict__ Bt,
                                                    float* __restrict__ C) {
  __shared__ short As[3][4][128][8];  // 8KB per buf
  __shared__ short Bs[3][4][64][8];   // 4KB per buf
  const int tid = threadIdx.x;
  const int lane = tid & 63, wid = tid >> 6;
  const int l15 = lane & 15, lg = lane >> 4;
  const int row0 = blockIdx.x * 128, col0 = blockIdx.y * 64;
  const int wm = wid >> 1, wn = wid & 1;
  f32x4 acc[4][2] = {};
  constexpr int NSTEP = D / 32;

  auto stage = [&](int k0, int nb) {  // 3 loads per thread
    #pragma unroll
    for (int it = 0; it < 2; ++it) {
      const int c = tid + it * 256;
      const int row = c & 127, kc2 = c >> 7;
      gll16(&A[(size_t)(row0 + row) * D + k0 + kc2 * 8],
            (char*)As + nb * 8192 + (wid * 64 + it * 256) * 16);
    }
    gll16(&Bt[(size_t)(col0 + lane) * D + k0 + wid * 8],
          (char*)Bs + nb * 4096 + wid * 1024);
  };

  stage(0, 0);
  stage(32, 1);
  for (int t = 0; t < NSTEP; ++t) {
    if (t < NSTEP - 1) asm volatile("s_waitcnt vmcnt(3)\ns_barrier" ::: "memory");
    else               asm volatile("s_waitcnt vmcnt(0)\ns_barrier" ::: "memory");
    if (t + 2 < NSTEP) stage((t + 2) * 32, (t + 2) % 3);
    const int cur = t % 3;
    short8 af[4], bfr[2];
    #pragma unroll
    for (int m = 0; m < 4; ++m) af[m] = *(const short8*)&As[cur][lg][wm * 64 + m * 16 + l15][0];
    #pragma unroll
    for (int n = 0; n < 2; ++n) bfr[n] = *(const short8*)&Bs[cur][lg][wn * 32 + n * 16 + l15][0];
    #pragma unroll
    for (int m = 0; m < 4; ++m)
      #pragma unroll
      for (int n = 0; n < 2; ++n)
        acc[m][n] = __builtin_amdgcn_mfma_f32_16x16x32_bf16(af[m], bfr[n], acc[m][n], 0, 0, 0);
  }
  #pragma unroll
  for (int m = 0; m < 4; ++m)
    #pragma unroll
    for (int r = 0; r < 4; ++r) {
      const int row = row0 + wm * 64 + m * 16 + 4 * lg + r;
      #pragma unroll
      for (int n = 0; n < 2; ++n)
        C[(size_t)row * D + col0 + wn * 32 + n * 16 + l15] = acc[m][n][r];
    }
}

// key permutation: QK chunk c, MFMA row i -> key (within 64-key half)
__device__ __forceinline__ int keyof(int c, int i) {
  return ((c >> 1) << 5) + ((i >> 2) << 3) + ((c & 1) << 2) + (i & 3);
}
// swizzled Vt byte address within one 8KB half-buffer: Vt[kc][d][ksb] = V[kc*8+ksb][d]
__device__ __forceinline__ int vt_byte(int kc, int d, int ksb) {
  return kc * 1024 + ((d ^ (kc & 7)) << 4) + ksb * 2;
}

// ---- causal flash attention: 8 waves share ONE 128-q-row tile; 128-key chunks,
// merged softmax, P in regs, K/V dbuf. Unpaired blocks, longest-first dispatch:
// qt = 15 - bid/32 (LPT); bid%32 = (b,h) -> KV sharers on same XCD.
__global__ __launch_bounds__(512, 4) void attn_kernel(const short* __restrict__ Qb,
                                                      const short* __restrict__ Kb,
                                                      const short* __restrict__ Vb,
                                                      const int* __restrict__ maskp,
                                                      const float* __restrict__ vsum,
                                                      short* __restrict__ ctxb) {
  __shared__ char KsBuf[2][16384];  // [buf][half*8192 + dc*1024 + c*256 + i*16]
  __shared__ char VtBuf[2][16384];  // [buf][half*8192 + vt_byte(kc,d,ksb)]
  const int bid = blockIdx.x;
  const int qt = 15 - (bid >> 5);        // longest blocks first
  const int bh = bid & 31;
  const int b = bh >> 4, h = bh & 15;
  const int tid = threadIdx.x, lane = tid & 63, wid = tid >> 6;
  const int l15 = lane & 15, lg = lane >> 4;
  const int ql = wid * 16 + l15;         // q-row within the 128-row tile (for score lanes)

  short8 qf[2];
  {
    const size_t o = (size_t)(b * S + qt * 128 + ql) * D + h * DK;
    qf[0] = *(const short8*)&Qb[o + lg * 8];
    qf[1] = *(const short8*)&Qb[o + 32 + lg * 8];
  }
  float m = NEGBIG, l = 0.f;
  f32x4 cx[4] = {};

  const int kkey = keyof(lg, l15);        // per-lane K staging key (pre-swizzled src)
  const int vu = tid & 63, dv = tid >> 6; // V staging: key pair {2vu,2vu+1}, d-octet dv
  const int vh = vu >> 5, vl = vu & 31;
  const int vkc = vl >> 2, vksb = (vl & 3) * 2;

  auto stageK = [&](int jc, int nb) {
    const size_t base = (size_t)(b * S + jc * 128 + kkey) * D + h * DK + wid * 8;
    gll16(&Kb[base], (char*)KsBuf + nb * 16384 + wid * 1024);
    gll16(&Kb[base + (size_t)64 * D], (char*)KsBuf + nb * 16384 + 8192 + wid * 1024);
  };
  auto loadV = [&](int jc, short8& va, short8& vb2) {
    const size_t vb0 = (size_t)(b * S + jc * 128 + 2 * vu) * D + h * DK + dv * 8;
    va = *(const short8*)&Vb[vb0];
    vb2 = *(const short8*)&Vb[vb0 + D];
  };
  auto writeV = [&](int nb, const short8& va, const short8& vb2) {
    char* dst = (char*)VtBuf + nb * 16384 + vh * 8192;
    #pragma unroll
    for (int i = 0; i < 8; ++i) {
      const unsigned w = (unsigned)(unsigned short)va[i] | ((unsigned)(unsigned short)vb2[i] << 16);
      *(unsigned*)(dst + vt_byte(vkc, dv * 8 + i, vksb)) = w;
    }
  };

  // one 128-key chunk: both halves' scores, ONE merged softmax, two PV steps
  auto tile_pair = [&](int nb, bool do1, bool mask0, bool mask1) {
    const char* ks0 = (const char*)KsBuf + nb * 16384;
    const char* ks1 = ks0 + 8192;
    const char* vt0 = (const char*)VtBuf + nb * 16384;
    const char* vt1 = vt0 + 8192;
    f32x4 sa0[4], sa1[4];
    #pragma unroll
    for (int c = 0; c < 4; ++c) {
      const short8 kf0 = *(const short8*)(ks0 + lg * 1024 + c * 256 + l15 * 16);
      const short8 kf1 = *(const short8*)(ks0 + (4 + lg) * 1024 + c * 256 + l15 * 16);
      f32x4 zz = {0.f, 0.f, 0.f, 0.f};
      zz = __builtin_amdgcn_mfma_f32_16x16x32_bf16(kf0, qf[0], zz, 0, 0, 0);
      zz = __builtin_amdgcn_mfma_f32_16x16x32_bf16(kf1, qf[1], zz, 0, 0, 0);
      sa0[c] = zz;
    }
    if (do1) {
      #pragma unroll
      for (int c = 0; c < 4; ++c) {
        const short8 kf0 = *(const short8*)(ks1 + lg * 1024 + c * 256 + l15 * 16);
        const short8 kf1 = *(const short8*)(ks1 + (4 + lg) * 1024 + c * 256 + l15 * 16);
        f32x4 zz = {0.f, 0.f, 0.f, 0.f};
        zz = __builtin_amdgcn_mfma_f32_16x16x32_bf16(kf0, qf[0], zz, 0, 0, 0);
        zz = __builtin_amdgcn_mfma_f32_16x16x32_bf16(kf1, qf[1], zz, 0, 0, 0);
        sa1[c] = zz;
      }
    }
    if (mask0) {  // diag, low waves: keys 0..63 vs ql 0..63
      #pragma unroll
      for (int c = 0; c < 4; ++c)
        #pragma unroll
        for (int r = 0; r < 4; ++r)
          if (((c >> 1) << 5) + (lg << 3) + ((c & 1) << 2) + r > ql) sa0[c][r] = NEGBIG;
    }
    if (do1 && mask1) {  // diag, high waves: keys 64..127 vs ql 64..127
      #pragma unroll
      for (int c = 0; c < 4; ++c)
        #pragma unroll
        for (int r = 0; r < 4; ++r)
          if (64 + ((c >> 1) << 5) + (lg << 3) + ((c & 1) << 2) + r > ql) sa1[c][r] = NEGBIG;
    }
    float pm = sa0[0][0];
    #pragma unroll
    for (int c = 0; c < 4; ++c)
      #pragma unroll
      for (int r = 0; r < 4; ++r) pm = fmaxf(pm, sa0[c][r]);
    if (do1)
      #pragma unroll
      for (int c = 0; c < 4; ++c)
        #pragma unroll
        for (int r = 0; r < 4; ++r) pm = fmaxf(pm, sa1[c][r]);
    pm = fmaxf(pm, __shfl_xor(pm, 16));
    pm = fmaxf(pm, __shfl_xor(pm, 32));
    if (pm > m + 8.f) {  // defer-max (T13); scores in log2 units
      const float sc = exp2f(m - pm);
      l *= sc;
      #pragma unroll
      for (int dt = 0; dt < 4; ++dt) cx[dt] *= sc;
      m = pm;
    }
    float rs = 0.f;
    #pragma unroll
    for (int c = 0; c < 4; ++c)
      #pragma unroll
      for (int r = 0; r < 4; ++r) {
        const float p = exp2f(sa0[c][r] - m);
        sa0[c][r] = p;
        rs += p;
      }
    if (do1)
      #pragma unroll
      for (int c = 0; c < 4; ++c)
        #pragma unroll
        for (int r = 0; r < 4; ++r) {
          const float p = exp2f(sa1[c][r] - m);
          sa1[c][r] = p;
          rs += p;
        }
    rs += __shfl_xor(rs, 16);
    rs += __shfl_xor(rs, 32);
    l += rs;
    {
      short8 pf[2];
      #pragma unroll
      for (int kk = 0; kk < 2; ++kk)
        #pragma unroll
        for (int jj = 0; jj < 8; ++jj)
          pf[kk][jj] = f2bf(sa0[kk * 2 + (jj >> 2)][jj & 3]);
      #pragma unroll
      for (int kk = 0; kk < 2; ++kk)
        #pragma unroll
        for (int dt = 0; dt < 4; ++dt) {
          const short8 vf = *(const short8*)(vt0 + vt_byte(kk * 4 + lg, dt * 16 + l15, 0));
          cx[dt] = __builtin_amdgcn_mfma_f32_16x16x32_bf16(vf, pf[kk], cx[dt], 0, 0, 0);
        }
    }
    if (do1) {
      short8 pf[2];
      #pragma unroll
      for (int kk = 0; kk < 2; ++kk)
        #pragma unroll
        for (int jj = 0; jj < 8; ++jj)
          pf[kk][jj] = f2bf(sa1[kk * 2 + (jj >> 2)][jj & 3]);
      #pragma unroll
      for (int kk = 0; kk < 2; ++kk)
        #pragma unroll
        for (int dt = 0; dt < 4; ++dt) {
          const short8 vf = *(const short8*)(vt1 + vt_byte(kk * 4 + lg, dt * 16 + l15, 0));
          cx[dt] = __builtin_amdgcn_mfma_f32_16x16x32_bf16(vf, pf[kk], cx[dt], 0, 0, 0);
        }
    }
  };

  {  // prologue: stage chunk 0 into buf 0
    short8 va, vb2;
    stageK(0, 0);
    loadV(0, va, vb2);
    writeV(0, va, vb2);
  }
  __syncthreads();
  int cur = 0;
  for (int jc = 0; jc <= qt; ++jc) {
    short8 nva, nvb;
    if (jc < qt) { stageK(jc + 1, cur ^ 1); loadV(jc + 1, nva, nvb); }  // issue early
    const bool diag = (jc == qt), hi = (wid >= 4);
    tile_pair(cur, !diag || hi, diag && !hi, diag && hi);
    if (jc < qt) writeV(cur ^ 1, nva, nvb);  // write late (T14)
    __syncthreads();
    cur ^= 1;
  }

  {  // epilogue: normalize; masked query rows -> mean(V) = vsum/S
    const int qg = qt * 128 + ql;
    const int mq = maskp[b * S + qg];
    const float inv = 1.0f / l;
    constexpr float vscale = 1.0f / S;
    short* orow = &ctxb[(size_t)(b * S + qg) * D + h * DK];
    const float* vmb = &vsum[(size_t)b * D + h * DK];
    #pragma unroll
    for (int dt = 0; dt < 4; ++dt)
      #pragma unroll
      for (int p2 = 0; p2 < 2; ++p2) {
        const int d = dt * 16 + 4 * lg + p2 * 2;
        const float v0 = mq ? vmb[d] * vscale     : cx[dt][p2 * 2] * inv;
        const float v1 = mq ? vmb[d + 1] * vscale : cx[dt][p2 * 2 + 1] * inv;
        *(unsigned*)&orow[d] = pack2bf(v0, v1);
      }
  }
}

extern "C" void kernel_launch(void* const* d_in, const int* in_sizes, int n_in,
                              void* d_out, int out_size, void* d_ws, size_t ws_size,
                              hipStream_t stream) {
  (void)in_sizes; (void)n_in; (void)out_size; (void)ws_size;
  const float* x   = (const float*)d_in[0];
  const float* enc = (const float*)d_in[1];
  const int*   msk = (const int*)d_in[2];
  const float* WQ  = (const float*)d_in[3];
  const float* WK  = (const float*)d_in[4];
  const float* WV  = (const float*)d_in[5];
  const float* WO  = (const float*)d_in[6];
  float* out = (float*)d_out;

  char* ws = (char*)d_ws;
  const size_t MB = 1u << 20;
  short* xb    = (short*)(ws + 0);          // 8 MB  (reused as ctxb)
  short* encb  = (short*)(ws + 8 * MB);     // 8 MB
  short* Qb    = (short*)(ws + 16 * MB);    // 8 MB each; Q,K,V contiguous
  short* WQt   = (short*)(ws + 40 * MB);    // 2 MB each; WQ,WK,WV,WO contiguous
  float* vsum  = (float*)(ws + 48 * MB);    // 8 KB
  short* Kb    = Qb + (size_t)M * D;
  short* Vb    = Kb + (size_t)M * D;
  short* WOt   = WQt + (size_t)3 * D * D;
  short* ctxb  = xb;

  hipMemsetAsync(vsum, 0, (size_t)B * D * sizeof(float), stream);

  prep_kernel<<<dim3(9216), 256, 0, stream>>>(x, enc, WQ, WK, WV, WO, xb, encb, WQt);

  gemm_qkv_kernel<<<dim3(M / 128, D / 128, 3), 256, 0, stream>>>(xb, encb, WQt, Qb, vsum);

  attn_kernel<<<dim3(512), 512, 0, stream>>>(Qb, Kb, Vb, msk, vsum, ctxb);

  gemmO_kernel<<<dim3(M / 128, D / 64), 256, 0, stream>>>(ctxb, WOt, out);
}